// Round 1
// baseline (1677.875 us; speedup 1.0000x reference)
//
#include <hip/hip_runtime.h>
#include <hip/hip_bf16.h>
#include <math.h>

// Problem constants (MambaBlock: D_MODEL=1024, D_STATE=16, D_CONV=4, EXPAND=2, DT_RANK=64)
#define NB      2
#define LSEQ    2048
#define BLTOK   4096      // NB * LSEQ
#define DM      1024
#define DI      2048      // EXPAND * DM
#define NST     16
#define DTR     64

// ---------------------------------------------------------------------------
// Generic fp32 GEMM: C[M,N] = A[M,K] @ W[N,K]^T  (both K-contiguous, row-major)
// 128x128 tile, K-step 16, 256 threads, 8x8 per thread.
// EPI 0: plain store.  EPI 1: softplus(acc + bias[n]).
// ---------------------------------------------------------------------------
template<int EPI>
__launch_bounds__(256)
__global__ void gemm_bt(const float* __restrict__ A, const float* __restrict__ W,
                        float* __restrict__ C, const float* __restrict__ bias,
                        int M, int N, int K, int lda, int ldb, int ldc)
{
    __shared__ float As[16][128];
    __shared__ float Bs[16][128];

    const int tid = threadIdx.x;
    const int tx = tid & 15;        // -> 8 output cols
    const int ty = tid >> 4;        // -> 8 output rows
    const int brow = blockIdx.y * 128;
    const int bcol = blockIdx.x * 128;

    const int mload = tid & 127;          // row within tile for staging
    const int kslot = (tid >> 7) * 8;     // 0 or 8

    const float* Aload = A + (size_t)(brow + mload) * lda + kslot;
    const int nrow = bcol + mload;
    const bool wvalid = (nrow < N);
    const float* Wload = W + (size_t)(wvalid ? nrow : 0) * ldb + kslot;

    float acc[8][8];
#pragma unroll
    for (int i = 0; i < 8; ++i)
#pragma unroll
        for (int j = 0; j < 8; ++j) acc[i][j] = 0.f;

    for (int k0 = 0; k0 < K; k0 += 16) {
        float4 a0 = *(const float4*)(Aload + k0);
        float4 a1 = *(const float4*)(Aload + k0 + 4);
        float4 b0 = make_float4(0.f, 0.f, 0.f, 0.f), b1 = b0;
        if (wvalid) {
            b0 = *(const float4*)(Wload + k0);
            b1 = *(const float4*)(Wload + k0 + 4);
        }
        __syncthreads();   // previous tile fully consumed
        As[kslot + 0][mload] = a0.x;  As[kslot + 1][mload] = a0.y;
        As[kslot + 2][mload] = a0.z;  As[kslot + 3][mload] = a0.w;
        As[kslot + 4][mload] = a1.x;  As[kslot + 5][mload] = a1.y;
        As[kslot + 6][mload] = a1.z;  As[kslot + 7][mload] = a1.w;
        Bs[kslot + 0][mload] = b0.x;  Bs[kslot + 1][mload] = b0.y;
        Bs[kslot + 2][mload] = b0.z;  Bs[kslot + 3][mload] = b0.w;
        Bs[kslot + 4][mload] = b1.x;  Bs[kslot + 5][mload] = b1.y;
        Bs[kslot + 6][mload] = b1.z;  Bs[kslot + 7][mload] = b1.w;
        __syncthreads();

#pragma unroll
        for (int kk = 0; kk < 16; ++kk) {
            float a[8], b[8];
            *(float4*)(a + 0) = *(const float4*)&As[kk][ty * 8 + 0];
            *(float4*)(a + 4) = *(const float4*)&As[kk][ty * 8 + 4];
            *(float4*)(b + 0) = *(const float4*)&Bs[kk][tx * 8 + 0];
            *(float4*)(b + 4) = *(const float4*)&Bs[kk][tx * 8 + 4];
#pragma unroll
            for (int i = 0; i < 8; ++i)
#pragma unroll
                for (int j = 0; j < 8; ++j)
                    acc[i][j] = fmaf(a[i], b[j], acc[i][j]);
        }
    }

#pragma unroll
    for (int i = 0; i < 8; ++i) {
        const int m = brow + ty * 8 + i;
        float* Crow = C + (size_t)m * ldc + bcol + tx * 8;
#pragma unroll
        for (int j = 0; j < 8; ++j) {
            const int n = bcol + tx * 8 + j;
            if (n < N) {
                float v = acc[i][j];
                if (EPI == 1) {
                    v += bias[n];
                    v = (v > 20.f) ? v : log1pf(__expf(v));   // softplus
                }
                Crow[j] = v;
            }
        }
    }
}

// ---------------------------------------------------------------------------
// Causal depthwise conv1d (width 4) + bias + silu.
// xz is [BLTOK, 2*DI]; x-part = cols [0, DI). One block per token row.
// ---------------------------------------------------------------------------
__launch_bounds__(256)
__global__ void conv_silu_kernel(const float* __restrict__ xz,
                                 const float* __restrict__ cw,
                                 const float* __restrict__ cb,
                                 float* __restrict__ u)
{
    const int bl = blockIdx.x;            // 0..BLTOK-1  (= b*LSEQ + l)
    const int l  = bl & (LSEQ - 1);
    for (int d = threadIdx.x; d < DI; d += 256) {
        float acc = cb[d];
#pragma unroll
        for (int k = 0; k < 4; ++k) {
            const int ls = l - 3 + k;
            if (ls >= 0)
                acc = fmaf(cw[d * 4 + k], xz[(size_t)(bl - 3 + k) * (2 * DI) + d], acc);
        }
        u[(size_t)bl * DI + d] = acc / (1.f + __expf(-acc));   // silu
    }
}

// ---------------------------------------------------------------------------
// Selective scan + skip + silu(z) gating.
// Thread layout: lane n = tid&15 (state index), dloc = tid>>4 (16 d per block).
// Grid: (DI/16, NB). LDS-staged tiles of TT timesteps.
// ---------------------------------------------------------------------------
#define TT 64
__launch_bounds__(256)
__global__ void scan_kernel(const float* __restrict__ delta,
                            const float* __restrict__ u,
                            const float* __restrict__ xdbl,
                            const float* __restrict__ A_log,
                            const float* __restrict__ Dskip,
                            const float* __restrict__ xz,
                            float* __restrict__ yg)
{
    __shared__ float s_dlt[TT][16], s_u[TT][16], s_B[TT][16], s_C[TT][16], s_z[TT][16];

    const int n    = threadIdx.x & 15;
    const int dloc = threadIdx.x >> 4;
    const int b    = blockIdx.y;
    const int d0   = blockIdx.x * 16;
    const int d    = d0 + dloc;

    const float Aval = -__expf(A_log[d * NST + n]);
    const float Dsk  = Dskip[d];
    float h = 0.f;

    for (int t0 = 0; t0 < LSEQ; t0 += TT) {
        __syncthreads();
        for (int i = threadIdx.x; i < TT * 16; i += 256) {
            const int tt = i >> 4, dd = i & 15;
            const size_t row = (size_t)(b * LSEQ + t0 + tt);
            s_dlt[tt][dd] = delta[row * DI + d0 + dd];
            s_u[tt][dd]   = u[row * DI + d0 + dd];
            s_B[tt][dd]   = xdbl[row * 96 + 64 + dd];
            s_C[tt][dd]   = xdbl[row * 96 + 80 + dd];
            s_z[tt][dd]   = xz[row * (2 * DI) + DI + d0 + dd];
        }
        __syncthreads();

        for (int tt = 0; tt < TT; ++tt) {
            const float dlt = s_dlt[tt][dloc];
            const float uu  = s_u[tt][dloc];
            const float Bv  = s_B[tt][n];
            const float Cv  = s_C[tt][n];
            const float dA  = __expf(dlt * Aval);
            h = fmaf(dA, h, dlt * uu * Bv);
            float y = h * Cv;
            y += __shfl_xor(y, 1, 16);
            y += __shfl_xor(y, 2, 16);
            y += __shfl_xor(y, 4, 16);
            y += __shfl_xor(y, 8, 16);
            if (n == 0) {
                const float zv  = s_z[tt][dloc];
                const float val = (y + uu * Dsk) * (zv / (1.f + __expf(-zv)));
                yg[(size_t)(b * LSEQ + t0 + tt) * DI + d] = val;
            }
        }
    }
}

// ---------------------------------------------------------------------------
extern "C" void kernel_launch(void* const* d_in, const int* in_sizes, int n_in,
                              void* d_out, int out_size, void* d_ws, size_t ws_size,
                              hipStream_t stream)
{
    const float* x        = (const float*)d_in[0];   // [2,2048,1024]
    const float* in_w     = (const float*)d_in[1];   // [4096,1024]
    const float* conv_w   = (const float*)d_in[2];   // [2048,1,4]
    const float* conv_b   = (const float*)d_in[3];   // [2048]
    const float* xproj_w  = (const float*)d_in[4];   // [96,2048]
    const float* dtproj_w = (const float*)d_in[5];   // [2048,64]
    const float* dtproj_b = (const float*)d_in[6];   // [2048]
    const float* A_log    = (const float*)d_in[7];   // [2048,16]
    const float* Dskip    = (const float*)d_in[8];   // [2048]
    const float* out_w    = (const float*)d_in[9];   // [1024,2048]
    float* out = (float*)d_out;

    // workspace layout (bytes)
    char* ws = (char*)d_ws;
    float* xz    = (float*)(ws);                            // [4096,4096] 64 MB
    float* u     = (float*)(ws + (size_t)64  * 1024 * 1024); // [4096,2048] 32 MB
    float* delta = (float*)(ws + (size_t)96  * 1024 * 1024); // [4096,2048] 32 MB
    float* xdbl  = (float*)(ws + (size_t)128 * 1024 * 1024); // [4096,96]  1.5 MB
    float* yg    = (float*)(ws + (size_t)130 * 1024 * 1024); // [4096,2048] 32 MB

    dim3 blk(256);

    // 1) in_proj: xz = x @ in_w^T   (M=4096, N=4096, K=1024)
    gemm_bt<0><<<dim3(32, 32), blk, 0, stream>>>(x, in_w, xz, nullptr,
                                                 BLTOK, 2 * DI, DM, DM, DM, 2 * DI);
    // 2) conv + silu -> u
    conv_silu_kernel<<<dim3(BLTOK), blk, 0, stream>>>(xz, conv_w, conv_b, u);
    // 3) x_proj: xdbl = u @ xproj_w^T  (M=4096, N=96, K=2048)
    gemm_bt<0><<<dim3(1, 32), blk, 0, stream>>>(u, xproj_w, xdbl, nullptr,
                                                BLTOK, DTR + 2 * NST, DI, DI, DI, 96);
    // 4) dt_proj + softplus: delta = softplus(xdbl[:, :64] @ dtproj_w^T + b)
    gemm_bt<1><<<dim3(16, 32), blk, 0, stream>>>(xdbl, dtproj_w, delta, dtproj_b,
                                                 BLTOK, DI, DTR, 96, DTR, DI);
    // 5) selective scan + D-skip + silu(z) gating -> yg
    scan_kernel<<<dim3(DI / 16, NB), blk, 0, stream>>>(delta, u, xdbl, A_log, Dskip, xz, yg);
    // 6) out_proj: out = yg @ out_w^T  (M=4096, N=1024, K=2048)
    gemm_bt<0><<<dim3(8, 32), blk, 0, stream>>>(yg, out_w, out, nullptr,
                                                BLTOK, DM, DI, DI, DI, DM);
}

// Round 2
// 374.206 us; speedup vs baseline: 4.4838x; 4.4838x over previous
//
#include <hip/hip_runtime.h>
#include <hip/hip_bf16.h>
#include <math.h>

// Problem constants (MambaBlock: D_MODEL=1024, D_STATE=16, D_CONV=4, EXPAND=2, DT_RANK=64)
#define NB      2
#define LSEQ    2048
#define BLTOK   4096      // NB * LSEQ
#define DM      1024
#define DI      2048      // EXPAND * DM
#define NST     16
#define DTR     64
#define CH      64        // scan chunks
#define LC      32        // LSEQ / CH

typedef __attribute__((ext_vector_type(8))) short short8;
typedef __attribute__((ext_vector_type(4))) float f32x4;

#define LDS_PTR(p) ((__attribute__((address_space(3))) void*)(p))
#define GLB_PTR(p) ((const __attribute__((address_space(1))) void*)(p))

static __device__ __forceinline__ unsigned short f2bf(float f) {
    unsigned int u = __float_as_uint(f);
    unsigned int r = (u + 0x7FFFu + ((u >> 16) & 1u)) >> 16;   // RNE
    return (unsigned short)r;
}

// ---------------------------------------------------------------------------
// fp32 -> bf16 cast (vector)
// ---------------------------------------------------------------------------
__launch_bounds__(256)
__global__ void cast_bf16(const float* __restrict__ in, unsigned short* __restrict__ out, int n4)
{
    int i = blockIdx.x * 256 + threadIdx.x;
    if (i < n4) {
        float4 v = ((const float4*)in)[i];
        uint2 o;
        o.x = (unsigned)f2bf(v.x) | ((unsigned)f2bf(v.y) << 16);
        o.y = (unsigned)f2bf(v.z) | ((unsigned)f2bf(v.w) << 16);
        ((uint2*)out)[i] = o;
    }
}

// ---------------------------------------------------------------------------
// bf16 MFMA GEMM: C[M,N] = A[M,K] @ W[N,K]^T, fp32 out.
// 128x128 tile, BK=32, 256 thr (4 waves 2x2), 16x16x32 MFMA, global_load_lds.
// Verified lane maps: A: row=l&15,k=(l>>4)*8+j ; B: col=l&15,same k ;
// D: col=lane&15, row=(lane>>4)*4+reg.
// ---------------------------------------------------------------------------
__launch_bounds__(256)
__global__ void gemm_mfma(const unsigned short* __restrict__ A,
                          const unsigned short* __restrict__ W,
                          float* __restrict__ C,
                          int M, int N, int K, int lda, int ldb, int ldc)
{
    __shared__ unsigned short Asub[128 * 32];
    __shared__ unsigned short Bsub[128 * 32];

    const int tid = threadIdx.x;
    const int l = tid & 63;
    const int w = tid >> 6;
    const int wr = w >> 1, wc = w & 1;
    const int brow = blockIdx.y * 128;
    const int bcol = blockIdx.x * 128;

    f32x4 acc[4][4];
#pragma unroll
    for (int i = 0; i < 4; ++i)
#pragma unroll
        for (int j = 0; j < 4; ++j) acc[i][j] = (f32x4)0.f;

    const int srow = tid >> 2;          // 0..63 (row within 64-row half)
    const int scol = (tid & 3) * 8;     // k-col elem within BK

    for (int k0 = 0; k0 < K; k0 += 32) {
#pragma unroll
        for (int i = 0; i < 2; ++i) {
            const int ar = brow + i * 64 + srow;
            const unsigned short* ga = A + (size_t)ar * lda + k0 + scol;
            __builtin_amdgcn_global_load_lds(GLB_PTR(ga),
                LDS_PTR((char*)Asub + i * 4096 + w * 1024), 16, 0, 0);
            int nr = bcol + i * 64 + srow;
            if (nr > N - 1) nr = N - 1;          // clamp (garbage cols never stored)
            const unsigned short* gb = W + (size_t)nr * ldb + k0 + scol;
            __builtin_amdgcn_global_load_lds(GLB_PTR(gb),
                LDS_PTR((char*)Bsub + i * 4096 + w * 1024), 16, 0, 0);
        }
        __syncthreads();

        short8 af[4], bf[4];
#pragma unroll
        for (int i = 0; i < 4; ++i) {
            const int row = wr * 64 + i * 16 + (l & 15);
            af[i] = *(const short8*)((const char*)Asub + row * 64 + (l >> 4) * 16);
        }
#pragma unroll
        for (int j = 0; j < 4; ++j) {
            const int row = wc * 64 + j * 16 + (l & 15);
            bf[j] = *(const short8*)((const char*)Bsub + row * 64 + (l >> 4) * 16);
        }
#pragma unroll
        for (int i = 0; i < 4; ++i)
#pragma unroll
            for (int j = 0; j < 4; ++j)
                acc[i][j] = __builtin_amdgcn_mfma_f32_16x16x32_bf16(af[i], bf[j], acc[i][j], 0, 0, 0);
        __syncthreads();
    }

#pragma unroll
    for (int i = 0; i < 4; ++i) {
        const int row0 = brow + wr * 64 + i * 16 + ((l >> 4) * 4);
#pragma unroll
        for (int j = 0; j < 4; ++j) {
            const int col = bcol + wc * 64 + j * 16 + (l & 15);
            if (col < N) {
#pragma unroll
                for (int r = 0; r < 4; ++r)
                    C[(size_t)(row0 + r) * ldc + col] = acc[i][j][r];
            }
        }
    }
}

// ---------------------------------------------------------------------------
// fp32 GEMM (kept for dt_proj, K=64): C = A @ W^T, softplus(acc+bias) epilogue.
// ---------------------------------------------------------------------------
__launch_bounds__(256)
__global__ void gemm_bt_sp(const float* __restrict__ A, const float* __restrict__ W,
                           float* __restrict__ C, const float* __restrict__ bias,
                           int M, int N, int K, int lda, int ldb, int ldc)
{
    __shared__ float As[16][128];
    __shared__ float Bs[16][128];

    const int tid = threadIdx.x;
    const int tx = tid & 15;
    const int ty = tid >> 4;
    const int brow = blockIdx.y * 128;
    const int bcol = blockIdx.x * 128;

    const int mload = tid & 127;
    const int kslot = (tid >> 7) * 8;

    const float* Aload = A + (size_t)(brow + mload) * lda + kslot;
    const float* Wload = W + (size_t)(bcol + mload) * ldb + kslot;

    float acc[8][8];
#pragma unroll
    for (int i = 0; i < 8; ++i)
#pragma unroll
        for (int j = 0; j < 8; ++j) acc[i][j] = 0.f;

    for (int k0 = 0; k0 < K; k0 += 16) {
        float4 a0 = *(const float4*)(Aload + k0);
        float4 a1 = *(const float4*)(Aload + k0 + 4);
        float4 b0 = *(const float4*)(Wload + k0);
        float4 b1 = *(const float4*)(Wload + k0 + 4);
        __syncthreads();
        As[kslot + 0][mload] = a0.x;  As[kslot + 1][mload] = a0.y;
        As[kslot + 2][mload] = a0.z;  As[kslot + 3][mload] = a0.w;
        As[kslot + 4][mload] = a1.x;  As[kslot + 5][mload] = a1.y;
        As[kslot + 6][mload] = a1.z;  As[kslot + 7][mload] = a1.w;
        Bs[kslot + 0][mload] = b0.x;  Bs[kslot + 1][mload] = b0.y;
        Bs[kslot + 2][mload] = b0.z;  Bs[kslot + 3][mload] = b0.w;
        Bs[kslot + 4][mload] = b1.x;  Bs[kslot + 5][mload] = b1.y;
        Bs[kslot + 6][mload] = b1.z;  Bs[kslot + 7][mload] = b1.w;
        __syncthreads();

#pragma unroll
        for (int kk = 0; kk < 16; ++kk) {
            float a[8], b[8];
            *(float4*)(a + 0) = *(const float4*)&As[kk][ty * 8 + 0];
            *(float4*)(a + 4) = *(const float4*)&As[kk][ty * 8 + 4];
            *(float4*)(b + 0) = *(const float4*)&Bs[kk][tx * 8 + 0];
            *(float4*)(b + 4) = *(const float4*)&Bs[kk][tx * 8 + 4];
#pragma unroll
            for (int i = 0; i < 8; ++i)
#pragma unroll
                for (int j = 0; j < 8; ++j)
                    acc[i][j] = fmaf(a[i], b[j], acc[i][j]);
        }
    }

#pragma unroll
    for (int i = 0; i < 8; ++i) {
        const int m = brow + ty * 8 + i;
        float* Crow = C + (size_t)m * ldc + bcol + tx * 8;
#pragma unroll
        for (int j = 0; j < 8; ++j) {
            const int n = bcol + tx * 8 + j;
            float v = acc[i][j] + bias[n];
            Crow[j] = (v > 20.f) ? v : log1pf(__expf(v));
        }
    }
}

// ---------------------------------------------------------------------------
// Causal depthwise conv1d (width 4) + bias + silu -> u (fp32) and ub (bf16)
// ---------------------------------------------------------------------------
__launch_bounds__(256)
__global__ void conv_silu_kernel(const float* __restrict__ xz,
                                 const float* __restrict__ cw,
                                 const float* __restrict__ cb,
                                 float* __restrict__ u,
                                 unsigned short* __restrict__ ub)
{
    const int bl = blockIdx.x;
    const int l  = bl & (LSEQ - 1);
    for (int d = threadIdx.x; d < DI; d += 256) {
        float acc = cb[d];
#pragma unroll
        for (int k = 0; k < 4; ++k) {
            const int ls = l - 3 + k;
            if (ls >= 0)
                acc = fmaf(cw[d * 4 + k], xz[(size_t)(bl - 3 + k) * (2 * DI) + d], acc);
        }
        float s = acc / (1.f + __expf(-acc));
        u[(size_t)bl * DI + d]  = s;
        ub[(size_t)bl * DI + d] = f2bf(s);
    }
}

// ---------------------------------------------------------------------------
// Scan phase 1: per chunk, per (b,d): 16 n-states in registers.
// P[n] = prod dA, S[n] = local end state from h=0.
// ---------------------------------------------------------------------------
__launch_bounds__(256)
__global__ void scan_phase1(const float* __restrict__ delta, const float* __restrict__ u,
                            const float* __restrict__ xdbl, const float* __restrict__ A_log,
                            float* __restrict__ P, float* __restrict__ S)
{
    __shared__ float sB[LC][NST];
    const int tid = threadIdx.x;
    const int d = blockIdx.x * 256 + tid;
    const int c = blockIdx.y;
    const int b = blockIdx.z;
    const int t0 = c * LC;

    for (int i = tid; i < LC * NST; i += 256) {
        const int tt = i >> 4, nn = i & 15;
        sB[tt][nn] = xdbl[(size_t)(b * LSEQ + t0 + tt) * 96 + 64 + nn];
    }
    __syncthreads();

    float Av[NST], Pv[NST], Sv[NST];
#pragma unroll
    for (int n = 0; n < NST; ++n) {
        Av[n] = -__expf(A_log[d * NST + n]) * 1.44269504f;   // log2 scale
        Pv[n] = 1.f; Sv[n] = 0.f;
    }

    const float* drow = delta + (size_t)(b * LSEQ + t0) * DI + d;
    const float* urow = u     + (size_t)(b * LSEQ + t0) * DI + d;

    for (int tg = 0; tg < LC; tg += 8) {
        float dl[8], uu[8];
#pragma unroll
        for (int q = 0; q < 8; ++q) {
            dl[q] = drow[(size_t)(tg + q) * DI];
            uu[q] = urow[(size_t)(tg + q) * DI];
        }
#pragma unroll
        for (int q = 0; q < 8; ++q) {
            const float du = dl[q] * uu[q];
#pragma unroll
            for (int n = 0; n < NST; ++n) {
                const float dA = exp2f(dl[q] * Av[n]);
                Pv[n] *= dA;
                Sv[n] = fmaf(dA, Sv[n], du * sB[tg + q][n]);
            }
        }
    }

    const size_t base = ((size_t)(b * CH + c) * DI + d) * NST;
#pragma unroll
    for (int n = 0; n < NST; n += 4) {
        *(f32x4*)&P[base + n] = (f32x4){Pv[n], Pv[n+1], Pv[n+2], Pv[n+3]};
        *(f32x4*)&S[base + n] = (f32x4){Sv[n], Sv[n+1], Sv[n+2], Sv[n+3]};
    }
}

// ---------------------------------------------------------------------------
// Scan phase 2: sequential combine over chunks. h_in[c] = state before chunk c.
// ---------------------------------------------------------------------------
__launch_bounds__(256)
__global__ void scan_phase2(const float* __restrict__ P, const float* __restrict__ S,
                            float* __restrict__ hin)
{
    const int g = blockIdx.x * 256 + threadIdx.x;   // B*DI*NST = 65536
    const int n = g & 15;
    const int d = (g >> 4) & (DI - 1);
    const int b = g >> 15;
    float h = 0.f;
#pragma unroll 4
    for (int c = 0; c < CH; ++c) {
        const size_t idx = ((size_t)(b * CH + c) * DI + d) * NST + n;
        hin[idx] = h;
        h = fmaf(P[idx], h, S[idx]);
    }
}

// ---------------------------------------------------------------------------
// Scan phase 3: replay chunk with correct h_in; fuse D-skip + silu(z) gating;
// write yg as bf16 (out_proj input).
// ---------------------------------------------------------------------------
__launch_bounds__(256)
__global__ void scan_phase3(const float* __restrict__ delta, const float* __restrict__ u,
                            const float* __restrict__ xdbl, const float* __restrict__ A_log,
                            const float* __restrict__ Dskip, const float* __restrict__ xz,
                            const float* __restrict__ hin, unsigned short* __restrict__ yg)
{
    __shared__ float sB[LC][NST], sC[LC][NST];
    const int tid = threadIdx.x;
    const int d = blockIdx.x * 256 + tid;
    const int c = blockIdx.y;
    const int b = blockIdx.z;
    const int t0 = c * LC;

    for (int i = tid; i < LC * NST; i += 256) {
        const int tt = i >> 4, nn = i & 15;
        const size_t row = (size_t)(b * LSEQ + t0 + tt) * 96;
        sB[tt][nn] = xdbl[row + 64 + nn];
        sC[tt][nn] = xdbl[row + 80 + nn];
    }
    __syncthreads();

    float Av[NST], h[NST];
#pragma unroll
    for (int n = 0; n < NST; ++n)
        Av[n] = -__expf(A_log[d * NST + n]) * 1.44269504f;

    const size_t hbase = ((size_t)(b * CH + c) * DI + d) * NST;
#pragma unroll
    for (int n = 0; n < NST; n += 4) {
        f32x4 t = *(const f32x4*)&hin[hbase + n];
        h[n] = t.x; h[n+1] = t.y; h[n+2] = t.z; h[n+3] = t.w;
    }
    const float Dskv = Dskip[d];

    const float* drow = delta + (size_t)(b * LSEQ + t0) * DI + d;
    const float* urow = u     + (size_t)(b * LSEQ + t0) * DI + d;
    const float* zrow = xz    + (size_t)(b * LSEQ + t0) * (2 * DI) + DI + d;
    unsigned short* yrow = yg + (size_t)(b * LSEQ + t0) * DI + d;

    for (int tg = 0; tg < LC; tg += 8) {
        float dl[8], uu[8], zz[8];
#pragma unroll
        for (int q = 0; q < 8; ++q) {
            dl[q] = drow[(size_t)(tg + q) * DI];
            uu[q] = urow[(size_t)(tg + q) * DI];
            zz[q] = zrow[(size_t)(tg + q) * (2 * DI)];
        }
#pragma unroll
        for (int q = 0; q < 8; ++q) {
            const float du = dl[q] * uu[q];
            float y = 0.f;
#pragma unroll
            for (int n = 0; n < NST; ++n) {
                const float dA = exp2f(dl[q] * Av[n]);
                h[n] = fmaf(dA, h[n], du * sB[tg + q][n]);
                y = fmaf(h[n], sC[tg + q][n], y);
            }
            const float zv = zz[q];
            const float sig = __frcp_rn(1.f + __expf(-zv));
            const float val = (y + uu[q] * Dskv) * (zv * sig);
            yrow[(size_t)(tg + q) * DI] = f2bf(val);
        }
    }
}

// ---------------------------------------------------------------------------
extern "C" void kernel_launch(void* const* d_in, const int* in_sizes, int n_in,
                              void* d_out, int out_size, void* d_ws, size_t ws_size,
                              hipStream_t stream)
{
    const float* x        = (const float*)d_in[0];
    const float* in_w     = (const float*)d_in[1];
    const float* conv_w   = (const float*)d_in[2];
    const float* conv_b   = (const float*)d_in[3];
    const float* xproj_w  = (const float*)d_in[4];
    const float* dtproj_w = (const float*)d_in[5];
    const float* dtproj_b = (const float*)d_in[6];
    const float* A_log    = (const float*)d_in[7];
    const float* Dskip    = (const float*)d_in[8];
    const float* out_w    = (const float*)d_in[9];
    float* out = (float*)d_out;

    char* ws = (char*)d_ws;
#define MB(x) ((size_t)(x) * 1024 * 1024)
    float*          xz    = (float*)(ws);                    // [4096,4096] 64 MB
    float*          u     = (float*)(ws + MB(64));           // [4096,2048] 32 MB
    float*          delta = (float*)(ws + MB(96));           // [4096,2048] 32 MB
    float*          xdbl  = (float*)(ws + MB(128));          // [4096,96]  1.5 MB
    unsigned short* ub    = (unsigned short*)(ws + MB(130)); // bf16 u     16 MB
    unsigned short* ygb   = (unsigned short*)(ws + MB(146)); // bf16 yg    16 MB
    float*          P     = (float*)(ws + MB(162));          // 16 MB
    float*          S     = (float*)(ws + MB(178));          // 16 MB
    float*          hin   = (float*)(ws + MB(194));          // 16 MB
    unsigned short* xb    = (unsigned short*)(ws + MB(210)); // bf16 x      8 MB
    unsigned short* wb1   = (unsigned short*)(ws + MB(218)); // bf16 in_w   8 MB
    unsigned short* wb3   = (unsigned short*)(ws + MB(226)); // bf16 xproj  0.4 MB
    unsigned short* wb6   = (unsigned short*)(ws + MB(227)); // bf16 out_w  4 MB

    dim3 blk(256);

    // casts (weights + activation input)
    cast_bf16<<<dim3((BLTOK * DM / 4 + 255) / 256), blk, 0, stream>>>(x, xb, BLTOK * DM / 4);
    cast_bf16<<<dim3((2 * DI * DM / 4 + 255) / 256), blk, 0, stream>>>(in_w, wb1, 2 * DI * DM / 4);
    cast_bf16<<<dim3((96 * DI / 4 + 255) / 256), blk, 0, stream>>>(xproj_w, wb3, 96 * DI / 4);
    cast_bf16<<<dim3((DM * DI / 4 + 255) / 256), blk, 0, stream>>>(out_w, wb6, DM * DI / 4);

    // 1) in_proj: xz = x @ in_w^T   [4096 x 4096], K=1024  (bf16 MFMA)
    gemm_mfma<<<dim3(32, 32), blk, 0, stream>>>(xb, wb1, xz, BLTOK, 2 * DI, DM, DM, DM, 2 * DI);

    // 2) conv + silu -> u (fp32) + ub (bf16)
    conv_silu_kernel<<<dim3(BLTOK), blk, 0, stream>>>(xz, conv_w, conv_b, u, ub);

    // 3) x_proj: xdbl = u @ xproj_w^T   [4096 x 96], K=2048  (bf16 MFMA, N-guard)
    gemm_mfma<<<dim3(1, 32), blk, 0, stream>>>(ub, wb3, xdbl, BLTOK, DTR + 2 * NST, DI, DI, DI, 96);

    // 4) dt_proj + softplus (fp32, K=64)
    gemm_bt_sp<<<dim3(16, 32), blk, 0, stream>>>(xdbl, dtproj_w, delta, dtproj_b,
                                                 BLTOK, DI, DTR, 96, DTR, DI);

    // 5) chunked selective scan
    scan_phase1<<<dim3(DI / 256, CH, NB), blk, 0, stream>>>(delta, u, xdbl, A_log, P, S);
    scan_phase2<<<dim3(NB * DI * NST / 256), blk, 0, stream>>>(P, S, hin);
    scan_phase3<<<dim3(DI / 256, CH, NB), blk, 0, stream>>>(delta, u, xdbl, A_log, Dskip,
                                                            xz, hin, ygb);

    // 6) out_proj: out = yg @ out_w^T   [4096 x 1024], K=2048  (bf16 MFMA)
    gemm_mfma<<<dim3(8, 32), blk, 0, stream>>>(ygb, wb6, out, BLTOK, DM, DI, DI, DI, DM);
}

// Round 3
// 324.052 us; speedup vs baseline: 5.1778x; 1.1548x over previous
//
#include <hip/hip_runtime.h>
#include <hip/hip_bf16.h>
#include <math.h>

// Problem constants (MambaBlock: D_MODEL=1024, D_STATE=16, D_CONV=4, EXPAND=2, DT_RANK=64)
#define NB      2
#define LSEQ    2048
#define BLTOK   4096      // NB * LSEQ
#define DM      1024
#define DI      2048      // EXPAND * DM
#define NST     16
#define DTR     64
#define CH      64        // scan chunks
#define LC      32        // LSEQ / CH

typedef __attribute__((ext_vector_type(8))) short short8;
typedef __attribute__((ext_vector_type(4))) float f32x4;

#define LDS_PTR(p) ((__attribute__((address_space(3))) void*)(p))
#define GLB_PTR(p) ((const __attribute__((address_space(1))) void*)(p))

static __device__ __forceinline__ unsigned short f2bf(float f) {
    unsigned int u = __float_as_uint(f);
    unsigned int r = (u + 0x7FFFu + ((u >> 16) & 1u)) >> 16;   // RNE
    return (unsigned short)r;
}

// ---------------------------------------------------------------------------
// fp32 -> bf16 cast (vector)
// ---------------------------------------------------------------------------
__launch_bounds__(256)
__global__ void cast_bf16(const float* __restrict__ in, unsigned short* __restrict__ out, int n4)
{
    int i = blockIdx.x * 256 + threadIdx.x;
    if (i < n4) {
        float4 v = ((const float4*)in)[i];
        uint2 o;
        o.x = (unsigned)f2bf(v.x) | ((unsigned)f2bf(v.y) << 16);
        o.y = (unsigned)f2bf(v.z) | ((unsigned)f2bf(v.w) << 16);
        ((uint2*)out)[i] = o;
    }
}

// ---------------------------------------------------------------------------
// bf16 MFMA GEMM: C[M,N] = A[M,K] @ W[N,K]^T, fp32 out.
// 128x128 tile, BK=32, 256 thr (4 waves 2x2), 16x16x32 MFMA, global_load_lds.
// ---------------------------------------------------------------------------
__launch_bounds__(256)
__global__ void gemm_mfma(const unsigned short* __restrict__ A,
                          const unsigned short* __restrict__ W,
                          float* __restrict__ C,
                          int M, int N, int K, int lda, int ldb, int ldc)
{
    __shared__ unsigned short Asub[128 * 32];
    __shared__ unsigned short Bsub[128 * 32];

    const int tid = threadIdx.x;
    const int l = tid & 63;
    const int w = tid >> 6;
    const int wr = w >> 1, wc = w & 1;
    const int brow = blockIdx.y * 128;
    const int bcol = blockIdx.x * 128;

    f32x4 acc[4][4];
#pragma unroll
    for (int i = 0; i < 4; ++i)
#pragma unroll
        for (int j = 0; j < 4; ++j) acc[i][j] = (f32x4)0.f;

    const int srow = tid >> 2;
    const int scol = (tid & 3) * 8;

    for (int k0 = 0; k0 < K; k0 += 32) {
#pragma unroll
        for (int i = 0; i < 2; ++i) {
            const int ar = brow + i * 64 + srow;
            const unsigned short* ga = A + (size_t)ar * lda + k0 + scol;
            __builtin_amdgcn_global_load_lds(GLB_PTR(ga),
                LDS_PTR((char*)Asub + i * 4096 + w * 1024), 16, 0, 0);
            int nr = bcol + i * 64 + srow;
            if (nr > N - 1) nr = N - 1;          // clamp (garbage cols never stored)
            const unsigned short* gb = W + (size_t)nr * ldb + k0 + scol;
            __builtin_amdgcn_global_load_lds(GLB_PTR(gb),
                LDS_PTR((char*)Bsub + i * 4096 + w * 1024), 16, 0, 0);
        }
        __syncthreads();

        short8 af[4], bf[4];
#pragma unroll
        for (int i = 0; i < 4; ++i) {
            const int row = wr * 64 + i * 16 + (l & 15);
            af[i] = *(const short8*)((const char*)Asub + row * 64 + (l >> 4) * 16);
        }
#pragma unroll
        for (int j = 0; j < 4; ++j) {
            const int row = wc * 64 + j * 16 + (l & 15);
            bf[j] = *(const short8*)((const char*)Bsub + row * 64 + (l >> 4) * 16);
        }
#pragma unroll
        for (int i = 0; i < 4; ++i)
#pragma unroll
            for (int j = 0; j < 4; ++j)
                acc[i][j] = __builtin_amdgcn_mfma_f32_16x16x32_bf16(af[i], bf[j], acc[i][j], 0, 0, 0);
        __syncthreads();
    }

#pragma unroll
    for (int i = 0; i < 4; ++i) {
        const int row0 = brow + wr * 64 + i * 16 + ((l >> 4) * 4);
#pragma unroll
        for (int j = 0; j < 4; ++j) {
            const int col = bcol + wc * 64 + j * 16 + (l & 15);
            if (col < N) {
#pragma unroll
                for (int r = 0; r < 4; ++r)
                    C[(size_t)(row0 + r) * ldc + col] = acc[i][j][r];
            }
        }
    }
}

// ---------------------------------------------------------------------------
// Split-K variant: blockIdx.z = k-slice; writes partial C per slice.
// ---------------------------------------------------------------------------
__launch_bounds__(256)
__global__ void gemm_mfma_sk(const unsigned short* __restrict__ A,
                             const unsigned short* __restrict__ W,
                             float* __restrict__ Cpart,
                             int M, int N, int K, int lda, int ldb, int ldc, int kslices)
{
    __shared__ unsigned short Asub[128 * 32];
    __shared__ unsigned short Bsub[128 * 32];

    const int tid = threadIdx.x;
    const int l = tid & 63;
    const int w = tid >> 6;
    const int wr = w >> 1, wc = w & 1;
    const int brow = blockIdx.y * 128;
    const int bcol = blockIdx.x * 128;
    const int ks = blockIdx.z;
    const int klen = K / kslices;
    const int kbeg = ks * klen;
    float* C = Cpart + (size_t)ks * M * ldc;

    f32x4 acc[4][4];
#pragma unroll
    for (int i = 0; i < 4; ++i)
#pragma unroll
        for (int j = 0; j < 4; ++j) acc[i][j] = (f32x4)0.f;

    const int srow = tid >> 2;
    const int scol = (tid & 3) * 8;

    for (int k0 = kbeg; k0 < kbeg + klen; k0 += 32) {
#pragma unroll
        for (int i = 0; i < 2; ++i) {
            const int ar = brow + i * 64 + srow;
            const unsigned short* ga = A + (size_t)ar * lda + k0 + scol;
            __builtin_amdgcn_global_load_lds(GLB_PTR(ga),
                LDS_PTR((char*)Asub + i * 4096 + w * 1024), 16, 0, 0);
            int nr = bcol + i * 64 + srow;
            if (nr > N - 1) nr = N - 1;
            const unsigned short* gb = W + (size_t)nr * ldb + k0 + scol;
            __builtin_amdgcn_global_load_lds(GLB_PTR(gb),
                LDS_PTR((char*)Bsub + i * 4096 + w * 1024), 16, 0, 0);
        }
        __syncthreads();

        short8 af[4], bf[4];
#pragma unroll
        for (int i = 0; i < 4; ++i) {
            const int row = wr * 64 + i * 16 + (l & 15);
            af[i] = *(const short8*)((const char*)Asub + row * 64 + (l >> 4) * 16);
        }
#pragma unroll
        for (int j = 0; j < 4; ++j) {
            const int row = wc * 64 + j * 16 + (l & 15);
            bf[j] = *(const short8*)((const char*)Bsub + row * 64 + (l >> 4) * 16);
        }
#pragma unroll
        for (int i = 0; i < 4; ++i)
#pragma unroll
            for (int j = 0; j < 4; ++j)
                acc[i][j] = __builtin_amdgcn_mfma_f32_16x16x32_bf16(af[i], bf[j], acc[i][j], 0, 0, 0);
        __syncthreads();
    }

#pragma unroll
    for (int i = 0; i < 4; ++i) {
        const int row0 = brow + wr * 64 + i * 16 + ((l >> 4) * 4);
#pragma unroll
        for (int j = 0; j < 4; ++j) {
            const int col = bcol + wc * 64 + j * 16 + (l & 15);
            if (col < N) {
#pragma unroll
                for (int r = 0; r < 4; ++r)
                    C[(size_t)(row0 + r) * ldc + col] = acc[i][j][r];
            }
        }
    }
}

// sum 8 partial slices -> xdbl  (float4-vectorized, n4 = total/4)
__launch_bounds__(256)
__global__ void sk_reduce(const float* __restrict__ part, float* __restrict__ out,
                          int n4, int slices)
{
    int i = blockIdx.x * 256 + threadIdx.x;
    if (i < n4) {
        float4 s = ((const float4*)part)[i];
        for (int k = 1; k < slices; ++k) {
            float4 p = ((const float4*)part)[(size_t)k * n4 + i];
            s.x += p.x; s.y += p.y; s.z += p.z; s.w += p.w;
        }
        ((float4*)out)[i] = s;
    }
}

// ---------------------------------------------------------------------------
// fp32 GEMM (dt_proj, K=64): C = A @ W^T, softplus(acc+bias) epilogue.
// ---------------------------------------------------------------------------
__launch_bounds__(256)
__global__ void gemm_bt_sp(const float* __restrict__ A, const float* __restrict__ W,
                           float* __restrict__ C, const float* __restrict__ bias,
                           int M, int N, int K, int lda, int ldb, int ldc)
{
    __shared__ float As[16][128];
    __shared__ float Bs[16][128];

    const int tid = threadIdx.x;
    const int tx = tid & 15;
    const int ty = tid >> 4;
    const int brow = blockIdx.y * 128;
    const int bcol = blockIdx.x * 128;

    const int mload = tid & 127;
    const int kslot = (tid >> 7) * 8;

    const float* Aload = A + (size_t)(brow + mload) * lda + kslot;
    const float* Wload = W + (size_t)(bcol + mload) * ldb + kslot;

    float acc[8][8];
#pragma unroll
    for (int i = 0; i < 8; ++i)
#pragma unroll
        for (int j = 0; j < 8; ++j) acc[i][j] = 0.f;

    for (int k0 = 0; k0 < K; k0 += 16) {
        float4 a0 = *(const float4*)(Aload + k0);
        float4 a1 = *(const float4*)(Aload + k0 + 4);
        float4 b0 = *(const float4*)(Wload + k0);
        float4 b1 = *(const float4*)(Wload + k0 + 4);
        __syncthreads();
        As[kslot + 0][mload] = a0.x;  As[kslot + 1][mload] = a0.y;
        As[kslot + 2][mload] = a0.z;  As[kslot + 3][mload] = a0.w;
        As[kslot + 4][mload] = a1.x;  As[kslot + 5][mload] = a1.y;
        As[kslot + 6][mload] = a1.z;  As[kslot + 7][mload] = a1.w;
        Bs[kslot + 0][mload] = b0.x;  Bs[kslot + 1][mload] = b0.y;
        Bs[kslot + 2][mload] = b0.z;  Bs[kslot + 3][mload] = b0.w;
        Bs[kslot + 4][mload] = b1.x;  Bs[kslot + 5][mload] = b1.y;
        Bs[kslot + 6][mload] = b1.z;  Bs[kslot + 7][mload] = b1.w;
        __syncthreads();

#pragma unroll
        for (int kk = 0; kk < 16; ++kk) {
            float a[8], b[8];
            *(float4*)(a + 0) = *(const float4*)&As[kk][ty * 8 + 0];
            *(float4*)(a + 4) = *(const float4*)&As[kk][ty * 8 + 4];
            *(float4*)(b + 0) = *(const float4*)&Bs[kk][tx * 8 + 0];
            *(float4*)(b + 4) = *(const float4*)&Bs[kk][tx * 8 + 4];
#pragma unroll
            for (int i = 0; i < 8; ++i)
#pragma unroll
                for (int j = 0; j < 8; ++j)
                    acc[i][j] = fmaf(a[i], b[j], acc[i][j]);
        }
    }

#pragma unroll
    for (int i = 0; i < 8; ++i) {
        const int m = brow + ty * 8 + i;
        float* Crow = C + (size_t)m * ldc + bcol + tx * 8;
#pragma unroll
        for (int j = 0; j < 8; ++j) {
            const int n = bcol + tx * 8 + j;
            float v = acc[i][j] + bias[n];
            Crow[j] = (v > 20.f) ? v : log1pf(__expf(v));
        }
    }
}

// ---------------------------------------------------------------------------
// Causal depthwise conv1d (width 4) + bias + silu -> u (fp32) and ub (bf16).
// XCD-chunked block swizzle: contiguous 512-token chunks per XCD for L2 reuse.
// ---------------------------------------------------------------------------
__launch_bounds__(256)
__global__ void conv_silu_kernel(const float* __restrict__ xz,
                                 const float* __restrict__ cw,
                                 const float* __restrict__ cb,
                                 float* __restrict__ u,
                                 unsigned short* __restrict__ ub)
{
    const int orig = blockIdx.x;
    const int bl = (orig & 7) * (BLTOK / 8) + (orig >> 3);   // bijective (4096%8==0)
    const int l  = bl & (LSEQ - 1);
    for (int d = threadIdx.x; d < DI; d += 256) {
        float acc = cb[d];
#pragma unroll
        for (int k = 0; k < 4; ++k) {
            const int ls = l - 3 + k;
            if (ls >= 0)
                acc = fmaf(cw[d * 4 + k], xz[(size_t)(bl - 3 + k) * (2 * DI) + d], acc);
        }
        float s = acc / (1.f + __expf(-acc));
        u[(size_t)bl * DI + d]  = s;
        ub[(size_t)bl * DI + d] = f2bf(s);
    }
}

// ---------------------------------------------------------------------------
// Scan phase 1: per chunk, per (b,d): 16 n-states in registers.
// LDS-staged 8-timestep sub-tiles (coalesced float4 loads).
// ---------------------------------------------------------------------------
__launch_bounds__(256)
__global__ void scan_phase1(const float* __restrict__ delta, const float* __restrict__ u,
                            const float* __restrict__ xdbl, const float* __restrict__ A_log,
                            float* __restrict__ P, float* __restrict__ S)
{
    __shared__ float s_d[8][256], s_u[8][256];
    __shared__ float sB[LC][NST];
    const int tid = threadIdx.x;
    const int d0 = blockIdx.x * 256;
    const int d  = d0 + tid;
    const int c = blockIdx.y;
    const int b = blockIdx.z;
    const int t0 = c * LC;

    for (int i = tid; i < LC * NST; i += 256)
        sB[i >> 4][i & 15] = xdbl[(size_t)(b * LSEQ + t0 + (i >> 4)) * 96 + 64 + (i & 15)];

    float Av[NST], Pv[NST], Sv[NST];
#pragma unroll
    for (int n = 0; n < NST; ++n) {
        Av[n] = -__expf(A_log[d * NST + n]) * 1.44269504f;
        Pv[n] = 1.f; Sv[n] = 0.f;
    }

    const float* dbase = delta + (size_t)(b * LSEQ + t0) * DI + d0;
    const float* ubase = u     + (size_t)(b * LSEQ + t0) * DI + d0;

    for (int sub = 0; sub < LC; sub += 8) {
        __syncthreads();
#pragma unroll
        for (int it = 0; it < 2; ++it) {
            const int slot = tid + it * 256;          // 512 float4 slots per array
            const int tt = slot >> 6, dq = (slot & 63) * 4;
            *(float4*)&s_d[tt][dq] = *(const float4*)(dbase + (size_t)(sub + tt) * DI + dq);
            *(float4*)&s_u[tt][dq] = *(const float4*)(ubase + (size_t)(sub + tt) * DI + dq);
        }
        __syncthreads();
#pragma unroll
        for (int q = 0; q < 8; ++q) {
            const float dlt = s_d[q][tid];
            const float uu  = s_u[q][tid];
            const float du  = dlt * uu;
#pragma unroll
            for (int n = 0; n < NST; ++n) {
                const float dA = __builtin_amdgcn_exp2f(dlt * Av[n]);
                Pv[n] *= dA;
                Sv[n] = fmaf(dA, Sv[n], du * sB[sub + q][n]);
            }
        }
    }

    const size_t base = ((size_t)(b * CH + c) * DI + d) * NST;
#pragma unroll
    for (int n = 0; n < NST; n += 4) {
        *(f32x4*)&P[base + n] = (f32x4){Pv[n], Pv[n+1], Pv[n+2], Pv[n+3]};
        *(f32x4*)&S[base + n] = (f32x4){Sv[n], Sv[n+1], Sv[n+2], Sv[n+3]};
    }
}

// ---------------------------------------------------------------------------
// Scan phase 2: sequential combine over chunks (coalesced layout).
// ---------------------------------------------------------------------------
__launch_bounds__(256)
__global__ void scan_phase2(const float* __restrict__ P, const float* __restrict__ S,
                            float* __restrict__ hin)
{
    const int g = blockIdx.x * 256 + threadIdx.x;
    const int n = g & 15;
    const int d = (g >> 4) & (DI - 1);
    const int b = g >> 15;
    float h = 0.f;
#pragma unroll 4
    for (int c = 0; c < CH; ++c) {
        const size_t idx = ((size_t)(b * CH + c) * DI + d) * NST + n;
        hin[idx] = h;
        h = fmaf(P[idx], h, S[idx]);
    }
}

// ---------------------------------------------------------------------------
// Scan phase 3: replay chunk with h_in; fuse D-skip + silu(z) gating; bf16 out.
// LDS-staged 8-timestep sub-tiles.
// ---------------------------------------------------------------------------
__launch_bounds__(256)
__global__ void scan_phase3(const float* __restrict__ delta, const float* __restrict__ u,
                            const float* __restrict__ xdbl, const float* __restrict__ A_log,
                            const float* __restrict__ Dskip, const float* __restrict__ xz,
                            const float* __restrict__ hin, unsigned short* __restrict__ yg)
{
    __shared__ float s_d[8][256], s_u[8][256], s_z[8][256];
    __shared__ float sB[LC][NST], sC[LC][NST];
    const int tid = threadIdx.x;
    const int d0 = blockIdx.x * 256;
    const int d  = d0 + tid;
    const int c = blockIdx.y;
    const int b = blockIdx.z;
    const int t0 = c * LC;

    for (int i = tid; i < LC * NST; i += 256) {
        const size_t row = (size_t)(b * LSEQ + t0 + (i >> 4)) * 96;
        sB[i >> 4][i & 15] = xdbl[row + 64 + (i & 15)];
        sC[i >> 4][i & 15] = xdbl[row + 80 + (i & 15)];
    }

    float Av[NST], h[NST];
#pragma unroll
    for (int n = 0; n < NST; ++n)
        Av[n] = -__expf(A_log[d * NST + n]) * 1.44269504f;

    const size_t hbase = ((size_t)(b * CH + c) * DI + d) * NST;
#pragma unroll
    for (int n = 0; n < NST; n += 4) {
        f32x4 t = *(const f32x4*)&hin[hbase + n];
        h[n] = t.x; h[n+1] = t.y; h[n+2] = t.z; h[n+3] = t.w;
    }
    const float Dskv = Dskip[d];

    const float* dbase = delta + (size_t)(b * LSEQ + t0) * DI + d0;
    const float* ubase = u     + (size_t)(b * LSEQ + t0) * DI + d0;
    const float* zbase = xz    + (size_t)(b * LSEQ + t0) * (2 * DI) + DI + d0;
    unsigned short* yrow = yg  + (size_t)(b * LSEQ + t0) * DI + d;

    for (int sub = 0; sub < LC; sub += 8) {
        __syncthreads();
#pragma unroll
        for (int it = 0; it < 2; ++it) {
            const int slot = tid + it * 256;
            const int tt = slot >> 6, dq = (slot & 63) * 4;
            *(float4*)&s_d[tt][dq] = *(const float4*)(dbase + (size_t)(sub + tt) * DI + dq);
            *(float4*)&s_u[tt][dq] = *(const float4*)(ubase + (size_t)(sub + tt) * DI + dq);
            *(float4*)&s_z[tt][dq] = *(const float4*)(zbase + (size_t)(sub + tt) * (2 * DI) + dq);
        }
        __syncthreads();
#pragma unroll
        for (int q = 0; q < 8; ++q) {
            const float dlt = s_d[q][tid];
            const float uu  = s_u[q][tid];
            const float du  = dlt * uu;
            float y = 0.f;
#pragma unroll
            for (int n = 0; n < NST; ++n) {
                const float dA = __builtin_amdgcn_exp2f(dlt * Av[n]);
                h[n] = fmaf(dA, h[n], du * sB[sub + q][n]);
                y = fmaf(h[n], sC[sub + q][n], y);
            }
            const float zv = s_z[q][tid];
            const float sig = __frcp_rn(1.f + __expf(-zv));
            const float val = (y + uu * Dskv) * (zv * sig);
            yrow[(size_t)(sub + q) * DI] = f2bf(val);
        }
    }
}

// ---------------------------------------------------------------------------
extern "C" void kernel_launch(void* const* d_in, const int* in_sizes, int n_in,
                              void* d_out, int out_size, void* d_ws, size_t ws_size,
                              hipStream_t stream)
{
    const float* x        = (const float*)d_in[0];
    const float* in_w     = (const float*)d_in[1];
    const float* conv_w   = (const float*)d_in[2];
    const float* conv_b   = (const float*)d_in[3];
    const float* xproj_w  = (const float*)d_in[4];
    const float* dtproj_w = (const float*)d_in[5];
    const float* dtproj_b = (const float*)d_in[6];
    const float* A_log    = (const float*)d_in[7];
    const float* Dskip    = (const float*)d_in[8];
    const float* out_w    = (const float*)d_in[9];
    float* out = (float*)d_out;

    char* ws = (char*)d_ws;
#define MB(x) ((size_t)(x) * 1024 * 1024)
    float*          xz    = (float*)(ws);                    // [4096,4096] 64 MB
    float*          u     = (float*)(ws + MB(64));           // [4096,2048] 32 MB
    float*          delta = (float*)(ws + MB(96));           // [4096,2048] 32 MB
    float*          xdbl  = (float*)(ws + MB(128));          // [4096,96]  1.5 MB
    unsigned short* ub    = (unsigned short*)(ws + MB(130)); // bf16 u     16 MB
    unsigned short* ygb   = (unsigned short*)(ws + MB(146)); // bf16 yg    16 MB
    float*          P     = (float*)(ws + MB(162));          // 16 MB (also x_proj partials, consumed before P written)
    float*          S     = (float*)(ws + MB(178));          // 16 MB
    float*          hin   = (float*)(ws + MB(194));          // 16 MB
    unsigned short* xb    = (unsigned short*)(ws + MB(210)); // bf16 x      8 MB
    unsigned short* wb1   = (unsigned short*)(ws + MB(218)); // bf16 in_w   8 MB
    unsigned short* wb3   = (unsigned short*)(ws + MB(226)); // bf16 xproj  0.4 MB
    unsigned short* wb6   = (unsigned short*)(ws + MB(227)); // bf16 out_w  4 MB
    float*          xdbl_part = P;                           // 8 x [4096,96] = 12.6 MB

    dim3 blk(256);

    cast_bf16<<<dim3((BLTOK * DM / 4 + 255) / 256), blk, 0, stream>>>(x, xb, BLTOK * DM / 4);
    cast_bf16<<<dim3((2 * DI * DM / 4 + 255) / 256), blk, 0, stream>>>(in_w, wb1, 2 * DI * DM / 4);
    cast_bf16<<<dim3((96 * DI / 4 + 255) / 256), blk, 0, stream>>>(xproj_w, wb3, 96 * DI / 4);
    cast_bf16<<<dim3((DM * DI / 4 + 255) / 256), blk, 0, stream>>>(out_w, wb6, DM * DI / 4);

    // 1) in_proj: xz = x @ in_w^T   [4096 x 4096], K=1024
    gemm_mfma<<<dim3(32, 32), blk, 0, stream>>>(xb, wb1, xz, BLTOK, 2 * DI, DM, DM, DM, 2 * DI);

    // 2) conv + silu -> u (fp32) + ub (bf16)
    conv_silu_kernel<<<dim3(BLTOK), blk, 0, stream>>>(xz, conv_w, conv_b, u, ub);

    // 3) x_proj split-K=8: partials then reduce   [4096 x 96], K=2048
    gemm_mfma_sk<<<dim3(1, 32, 8), blk, 0, stream>>>(ub, wb3, xdbl_part,
                                                     BLTOK, DTR + 2 * NST, DI, DI, DI, 96, 8);
    sk_reduce<<<dim3((BLTOK * 96 / 4 + 255) / 256), blk, 0, stream>>>(xdbl_part, xdbl,
                                                                      BLTOK * 96 / 4, 8);

    // 4) dt_proj + softplus (fp32, K=64)
    gemm_bt_sp<<<dim3(16, 32), blk, 0, stream>>>(xdbl, dtproj_w, delta, dtproj_b,
                                                 BLTOK, DI, DTR, 96, DTR, DI);

    // 5) chunked selective scan
    scan_phase1<<<dim3(DI / 256, CH, NB), blk, 0, stream>>>(delta, u, xdbl, A_log, P, S);
    scan_phase2<<<dim3(NB * DI * NST / 256), blk, 0, stream>>>(P, S, hin);
    scan_phase3<<<dim3(DI / 256, CH, NB), blk, 0, stream>>>(delta, u, xdbl, A_log, Dskip,
                                                            xz, hin, ygb);

    // 6) out_proj: out = yg @ out_w^T   [4096 x 1024], K=2048
    gemm_mfma<<<dim3(8, 32), blk, 0, stream>>>(ygb, wb6, out, BLTOK, DM, DI, DI, DI, DM);
}

// Round 4
// 277.744 us; speedup vs baseline: 6.0411x; 1.1667x over previous
//
#include <hip/hip_runtime.h>
#include <hip/hip_bf16.h>
#include <math.h>

// Problem constants (MambaBlock: D_MODEL=1024, D_STATE=16, D_CONV=4, EXPAND=2, DT_RANK=64)
#define NB      2
#define LSEQ    2048
#define BLTOK   4096      // NB * LSEQ
#define DM      1024
#define DI      2048      // EXPAND * DM
#define NST     16
#define DTR     64
#define CH      64        // scan chunks
#define LC      32        // LSEQ / CH

typedef __attribute__((ext_vector_type(8))) short short8;
typedef __attribute__((ext_vector_type(4))) float f32x4;

#define LDS_PTR(p) ((__attribute__((address_space(3))) void*)(p))
#define GLB_PTR(p) ((const __attribute__((address_space(1))) void*)(p))

static __device__ __forceinline__ unsigned short f2bf(float f) {
    unsigned int u = __float_as_uint(f);
    unsigned int r = (u + 0x7FFFu + ((u >> 16) & 1u)) >> 16;   // RNE
    return (unsigned short)r;
}
static __device__ __forceinline__ float bf2f(unsigned short v) {
    return __uint_as_float((unsigned int)v << 16);
}

// ---------------------------------------------------------------------------
// fp32 -> bf16 cast (vector)
// ---------------------------------------------------------------------------
__launch_bounds__(256)
__global__ void cast_bf16(const float* __restrict__ in, unsigned short* __restrict__ out, int n4)
{
    int i = blockIdx.x * 256 + threadIdx.x;
    if (i < n4) {
        float4 v = ((const float4*)in)[i];
        uint2 o;
        o.x = (unsigned)f2bf(v.x) | ((unsigned)f2bf(v.y) << 16);
        o.y = (unsigned)f2bf(v.z) | ((unsigned)f2bf(v.w) << 16);
        ((uint2*)out)[i] = o;
    }
}

// ---------------------------------------------------------------------------
// bf16 MFMA GEMM, BK=64 double-buffered 2-phase pipeline (T3-minimum):
//   stage(next) -> ds_read+MFMA(cur) -> barrier (compiler drains vmcnt there,
//   covered by the MFMA phase) -> swap.  One barrier per K-tile.
// LDS XOR swizzle (both-sides, rule #21): 16B slot s within each 128B row
// holds global slot s ^ (row&7); reads XOR the same term -> ~2-way conflicts.
// Requires M,N multiples of 128, K multiple of 64.
// BF16OUT=1: bf16 C; else fp32 C.
// ---------------------------------------------------------------------------
template<int BF16OUT>
__launch_bounds__(256)
__global__ void gemm_db(const unsigned short* __restrict__ A,
                        const unsigned short* __restrict__ W,
                        void* __restrict__ Cout,
                        int M, int N, int K, int lda, int ldb, int ldc)
{
    __shared__ unsigned short lds[2][2][128 * 64];   // 64 KB: [buf][A/B][row*64+col]

    const int tid = threadIdx.x;
    const int l = tid & 63;
    const int w = tid >> 6;
    const int wr = w >> 1, wc = w & 1;
    const int brow = blockIdx.y * 128;
    const int bcol = blockIdx.x * 128;

    // staging: issue i covers rows i*32..i*32+31; thread -> (row=tid>>3, slot=tid&7)
    const int strow = tid >> 3;                          // 0..31
    const int scol  = ((tid & 7) ^ (strow & 7)) * 8;     // swizzled source col (elems)

    f32x4 acc[4][4];
#pragma unroll
    for (int i = 0; i < 4; ++i)
#pragma unroll
        for (int j = 0; j < 4; ++j) acc[i][j] = (f32x4)0.f;

    auto stage = [&](int bb, int k0) {
#pragma unroll
        for (int i = 0; i < 4; ++i) {
            const unsigned short* ga = A + (size_t)(brow + i * 32 + strow) * lda + k0 + scol;
            __builtin_amdgcn_global_load_lds(GLB_PTR(ga),
                LDS_PTR((char*)&lds[bb][0][0] + (i * 32 + w * 8) * 128), 16, 0, 0);
            const unsigned short* gb = W + (size_t)(bcol + i * 32 + strow) * ldb + k0 + scol;
            __builtin_amdgcn_global_load_lds(GLB_PTR(gb),
                LDS_PTR((char*)&lds[bb][1][0] + (i * 32 + w * 8) * 128), 16, 0, 0);
        }
    };

    auto compute = [&](int bb) {
        const char* baseA = (const char*)&lds[bb][0][0];
        const char* baseB = (const char*)&lds[bb][1][0];
        const int xo  = (l & 7) * 16;          // row&7 == l&7 for all frag rows
        const int ko0 = (l >> 4) * 16;
#pragma unroll
        for (int ks = 0; ks < 2; ++ks) {
            const int kb = ks * 64 + ko0;
            short8 af[4], bfr[4];
#pragma unroll
            for (int i = 0; i < 4; ++i) {
                const int rowA = wr * 64 + i * 16 + (l & 15);
                af[i] = *(const short8*)(baseA + rowA * 128 + (kb ^ xo));
                const int rowB = wc * 64 + i * 16 + (l & 15);
                bfr[i] = *(const short8*)(baseB + rowB * 128 + (kb ^ xo));
            }
#pragma unroll
            for (int i = 0; i < 4; ++i)
#pragma unroll
                for (int j = 0; j < 4; ++j)
                    acc[i][j] = __builtin_amdgcn_mfma_f32_16x16x32_bf16(af[i], bfr[j], acc[i][j], 0, 0, 0);
        }
    };

    const int nt = K / 64;
    stage(0, 0);
    __syncthreads();
    int cur = 0;
    for (int t = 0; t < nt - 1; ++t) {
        stage(cur ^ 1, (t + 1) * 64);
        compute(cur);
        __syncthreads();
        cur ^= 1;
    }
    compute(cur);

#pragma unroll
    for (int i = 0; i < 4; ++i) {
        const int row0 = brow + wr * 64 + i * 16 + ((l >> 4) * 4);
#pragma unroll
        for (int j = 0; j < 4; ++j) {
            const int col = bcol + wc * 64 + j * 16 + (l & 15);
            if (BF16OUT) {
                unsigned short* Cb = (unsigned short*)Cout;
#pragma unroll
                for (int r = 0; r < 4; ++r)
                    Cb[(size_t)(row0 + r) * ldc + col] = f2bf(acc[i][j][r]);
            } else {
                float* Cf = (float*)Cout;
#pragma unroll
                for (int r = 0; r < 4; ++r)
                    Cf[(size_t)(row0 + r) * ldc + col] = acc[i][j][r];
            }
        }
    }
}

// ---------------------------------------------------------------------------
// Split-K MFMA GEMM for x_proj (N=96): blockIdx.z = k-slice, partial C out.
// ---------------------------------------------------------------------------
__launch_bounds__(256)
__global__ void gemm_mfma_sk(const unsigned short* __restrict__ A,
                             const unsigned short* __restrict__ W,
                             float* __restrict__ Cpart,
                             int M, int N, int K, int lda, int ldb, int ldc, int kslices)
{
    __shared__ unsigned short Asub[128 * 32];
    __shared__ unsigned short Bsub[128 * 32];

    const int tid = threadIdx.x;
    const int l = tid & 63;
    const int w = tid >> 6;
    const int wr = w >> 1, wc = w & 1;
    const int brow = blockIdx.y * 128;
    const int bcol = blockIdx.x * 128;
    const int ks = blockIdx.z;
    const int klen = K / kslices;
    const int kbeg = ks * klen;
    float* C = Cpart + (size_t)ks * M * ldc;

    f32x4 acc[4][4];
#pragma unroll
    for (int i = 0; i < 4; ++i)
#pragma unroll
        for (int j = 0; j < 4; ++j) acc[i][j] = (f32x4)0.f;

    const int srow = tid >> 2;
    const int scol = (tid & 3) * 8;

    for (int k0 = kbeg; k0 < kbeg + klen; k0 += 32) {
#pragma unroll
        for (int i = 0; i < 2; ++i) {
            const int ar = brow + i * 64 + srow;
            const unsigned short* ga = A + (size_t)ar * lda + k0 + scol;
            __builtin_amdgcn_global_load_lds(GLB_PTR(ga),
                LDS_PTR((char*)Asub + i * 4096 + w * 1024), 16, 0, 0);
            int nr = bcol + i * 64 + srow;
            if (nr > N - 1) nr = N - 1;
            const unsigned short* gb = W + (size_t)nr * ldb + k0 + scol;
            __builtin_amdgcn_global_load_lds(GLB_PTR(gb),
                LDS_PTR((char*)Bsub + i * 4096 + w * 1024), 16, 0, 0);
        }
        __syncthreads();

        short8 af[4], bf[4];
#pragma unroll
        for (int i = 0; i < 4; ++i) {
            const int row = wr * 64 + i * 16 + (l & 15);
            af[i] = *(const short8*)((const char*)Asub + row * 64 + (l >> 4) * 16);
        }
#pragma unroll
        for (int j = 0; j < 4; ++j) {
            const int row = wc * 64 + j * 16 + (l & 15);
            bf[j] = *(const short8*)((const char*)Bsub + row * 64 + (l >> 4) * 16);
        }
#pragma unroll
        for (int i = 0; i < 4; ++i)
#pragma unroll
            for (int j = 0; j < 4; ++j)
                acc[i][j] = __builtin_amdgcn_mfma_f32_16x16x32_bf16(af[i], bf[j], acc[i][j], 0, 0, 0);
        __syncthreads();
    }

#pragma unroll
    for (int i = 0; i < 4; ++i) {
        const int row0 = brow + wr * 64 + i * 16 + ((l >> 4) * 4);
#pragma unroll
        for (int j = 0; j < 4; ++j) {
            const int col = bcol + wc * 64 + j * 16 + (l & 15);
            if (col < N) {
#pragma unroll
                for (int r = 0; r < 4; ++r)
                    C[(size_t)(row0 + r) * ldc + col] = acc[i][j][r];
            }
        }
    }
}

// sum partial slices -> xdbl
__launch_bounds__(256)
__global__ void sk_reduce(const float* __restrict__ part, float* __restrict__ out,
                          int n4, int slices)
{
    int i = blockIdx.x * 256 + threadIdx.x;
    if (i < n4) {
        float4 s = ((const float4*)part)[i];
        for (int k = 1; k < slices; ++k) {
            float4 p = ((const float4*)part)[(size_t)k * n4 + i];
            s.x += p.x; s.y += p.y; s.z += p.z; s.w += p.w;
        }
        ((float4*)out)[i] = s;
    }
}

// ---------------------------------------------------------------------------
// fp32 GEMM (dt_proj, K=64): C = A @ W^T, softplus(acc+bias) epilogue.
// ---------------------------------------------------------------------------
__launch_bounds__(256)
__global__ void gemm_bt_sp(const float* __restrict__ A, const float* __restrict__ W,
                           float* __restrict__ C, const float* __restrict__ bias,
                           int M, int N, int K, int lda, int ldb, int ldc)
{
    __shared__ float As[16][128];
    __shared__ float Bs[16][128];

    const int tid = threadIdx.x;
    const int tx = tid & 15;
    const int ty = tid >> 4;
    const int brow = blockIdx.y * 128;
    const int bcol = blockIdx.x * 128;

    const int mload = tid & 127;
    const int kslot = (tid >> 7) * 8;

    const float* Aload = A + (size_t)(brow + mload) * lda + kslot;
    const float* Wload = W + (size_t)(bcol + mload) * ldb + kslot;

    float acc[8][8];
#pragma unroll
    for (int i = 0; i < 8; ++i)
#pragma unroll
        for (int j = 0; j < 8; ++j) acc[i][j] = 0.f;

    for (int k0 = 0; k0 < K; k0 += 16) {
        float4 a0 = *(const float4*)(Aload + k0);
        float4 a1 = *(const float4*)(Aload + k0 + 4);
        float4 b0 = *(const float4*)(Wload + k0);
        float4 b1 = *(const float4*)(Wload + k0 + 4);
        __syncthreads();
        As[kslot + 0][mload] = a0.x;  As[kslot + 1][mload] = a0.y;
        As[kslot + 2][mload] = a0.z;  As[kslot + 3][mload] = a0.w;
        As[kslot + 4][mload] = a1.x;  As[kslot + 5][mload] = a1.y;
        As[kslot + 6][mload] = a1.z;  As[kslot + 7][mload] = a1.w;
        Bs[kslot + 0][mload] = b0.x;  Bs[kslot + 1][mload] = b0.y;
        Bs[kslot + 2][mload] = b0.z;  Bs[kslot + 3][mload] = b0.w;
        Bs[kslot + 4][mload] = b1.x;  Bs[kslot + 5][mload] = b1.y;
        Bs[kslot + 6][mload] = b1.z;  Bs[kslot + 7][mload] = b1.w;
        __syncthreads();

#pragma unroll
        for (int kk = 0; kk < 16; ++kk) {
            float a[8], b[8];
            *(float4*)(a + 0) = *(const float4*)&As[kk][ty * 8 + 0];
            *(float4*)(a + 4) = *(const float4*)&As[kk][ty * 8 + 4];
            *(float4*)(b + 0) = *(const float4*)&Bs[kk][tx * 8 + 0];
            *(float4*)(b + 4) = *(const float4*)&Bs[kk][tx * 8 + 4];
#pragma unroll
            for (int i = 0; i < 8; ++i)
#pragma unroll
                for (int j = 0; j < 8; ++j)
                    acc[i][j] = fmaf(a[i], b[j], acc[i][j]);
        }
    }

#pragma unroll
    for (int i = 0; i < 8; ++i) {
        const int m = brow + ty * 8 + i;
        float* Crow = C + (size_t)m * ldc + bcol + tx * 8;
#pragma unroll
        for (int j = 0; j < 8; ++j) {
            const int n = bcol + tx * 8 + j;
            float v = acc[i][j] + bias[n];
            Crow[j] = (v > 20.f) ? v : log1pf(__expf(v));
        }
    }
}

// ---------------------------------------------------------------------------
// Causal depthwise conv1d (width 4) + bias + silu.  bf16 in (xz), bf16 out (u).
// Vectorized short8; XCD-chunked block swizzle.
// ---------------------------------------------------------------------------
__launch_bounds__(256)
__global__ void conv_silu_kernel(const unsigned short* __restrict__ xzb,
                                 const float* __restrict__ cw,
                                 const float* __restrict__ cb,
                                 unsigned short* __restrict__ ub)
{
    const int orig = blockIdx.x;
    const int bl = (orig & 7) * (BLTOK / 8) + (orig >> 3);   // bijective (4096%8==0)
    const int l  = bl & (LSEQ - 1);
    const int d0 = threadIdx.x * 8;

    float acc[8];
    float4 w4[8];
#pragma unroll
    for (int q = 0; q < 8; ++q) {
        w4[q]  = *(const float4*)&cw[(d0 + q) * 4];
        acc[q] = cb[d0 + q];
    }
#pragma unroll
    for (int k = 0; k < 4; ++k) {
        const int ls = l - 3 + k;
        if (ls < 0) continue;
        short8 v = *(const short8*)&xzb[(size_t)(bl - 3 + k) * (2 * DI) + d0];
        const float* wp0 = (const float*)&w4[0];
#pragma unroll
        for (int q = 0; q < 8; ++q) {
            const float wk = ((const float*)&w4[q])[k];   // k compile-time (unrolled)
            acc[q] = fmaf(wk, bf2f((unsigned short)v[q]), acc[q]);
        }
        (void)wp0;
    }
    short8 o;
#pragma unroll
    for (int q = 0; q < 8; ++q) {
        const float s = acc[q] / (1.f + __expf(-acc[q]));
        o[q] = (short)f2bf(s);
    }
    *(short8*)&ub[(size_t)bl * DI + d0] = o;
}

// ---------------------------------------------------------------------------
// Scan phase 1: per chunk, per (b,d): 16 n-states in registers.
// LDS-staged 8-timestep sub-tiles. delta fp32, u bf16.
// ---------------------------------------------------------------------------
__launch_bounds__(256)
__global__ void scan_phase1(const float* __restrict__ delta, const unsigned short* __restrict__ ub,
                            const float* __restrict__ xdbl, const float* __restrict__ A_log,
                            float* __restrict__ P, float* __restrict__ S)
{
    __shared__ float s_d[8][256];
    __shared__ unsigned short s_u[8][256];
    __shared__ float sB[LC][NST];
    const int tid = threadIdx.x;
    const int d0 = blockIdx.x * 256;
    const int d  = d0 + tid;
    const int c = blockIdx.y;
    const int b = blockIdx.z;
    const int t0 = c * LC;

    for (int i = tid; i < LC * NST; i += 256)
        sB[i >> 4][i & 15] = xdbl[(size_t)(b * LSEQ + t0 + (i >> 4)) * 96 + 64 + (i & 15)];

    float Av[NST], Pv[NST], Sv[NST];
#pragma unroll
    for (int n = 0; n < NST; ++n) {
        Av[n] = -__expf(A_log[d * NST + n]) * 1.44269504f;
        Pv[n] = 1.f; Sv[n] = 0.f;
    }

    const float*          dbase = delta + (size_t)(b * LSEQ + t0) * DI + d0;
    const unsigned short* ubase = ub    + (size_t)(b * LSEQ + t0) * DI + d0;

    for (int sub = 0; sub < LC; sub += 8) {
        __syncthreads();
#pragma unroll
        for (int it = 0; it < 2; ++it) {
            const int slot = tid + it * 256;
            const int tt = slot >> 6, dq = (slot & 63) * 4;
            *(float4*)&s_d[tt][dq] = *(const float4*)(dbase + (size_t)(sub + tt) * DI + dq);
        }
        {
            const int tt = tid >> 5, d8 = (tid & 31) * 8;
            *(short8*)&s_u[tt][d8] = *(const short8*)(ubase + (size_t)(sub + tt) * DI + d8);
        }
        __syncthreads();
#pragma unroll
        for (int q = 0; q < 8; ++q) {
            const float dlt = s_d[q][tid];
            const float uu  = bf2f(s_u[q][tid]);
            const float du  = dlt * uu;
#pragma unroll
            for (int n = 0; n < NST; ++n) {
                const float dA = __builtin_amdgcn_exp2f(dlt * Av[n]);
                Pv[n] *= dA;
                Sv[n] = fmaf(dA, Sv[n], du * sB[sub + q][n]);
            }
        }
    }

    const size_t base = ((size_t)(b * CH + c) * DI + d) * NST;
#pragma unroll
    for (int n = 0; n < NST; n += 4) {
        *(f32x4*)&P[base + n] = (f32x4){Pv[n], Pv[n+1], Pv[n+2], Pv[n+3]};
        *(f32x4*)&S[base + n] = (f32x4){Sv[n], Sv[n+1], Sv[n+2], Sv[n+3]};
    }
}

// ---------------------------------------------------------------------------
// Scan phase 2: sequential combine over chunks.
// ---------------------------------------------------------------------------
__launch_bounds__(256)
__global__ void scan_phase2(const float* __restrict__ P, const float* __restrict__ S,
                            float* __restrict__ hin)
{
    const int g = blockIdx.x * 256 + threadIdx.x;
    const int n = g & 15;
    const int d = (g >> 4) & (DI - 1);
    const int b = g >> 15;
    float h = 0.f;
#pragma unroll 4
    for (int c = 0; c < CH; ++c) {
        const size_t idx = ((size_t)(b * CH + c) * DI + d) * NST + n;
        hin[idx] = h;
        h = fmaf(P[idx], h, S[idx]);
    }
}

// ---------------------------------------------------------------------------
// Scan phase 3: replay chunk with h_in; fuse D-skip + silu(z) gating; bf16 out.
// delta fp32; u, z bf16.
// ---------------------------------------------------------------------------
__launch_bounds__(256)
__global__ void scan_phase3(const float* __restrict__ delta, const unsigned short* __restrict__ ub,
                            const float* __restrict__ xdbl, const float* __restrict__ A_log,
                            const float* __restrict__ Dskip, const unsigned short* __restrict__ xzb,
                            const float* __restrict__ hin, unsigned short* __restrict__ yg)
{
    __shared__ float s_d[8][256];
    __shared__ unsigned short s_u[8][256], s_z[8][256];
    __shared__ float sB[LC][NST], sC[LC][NST];
    const int tid = threadIdx.x;
    const int d0 = blockIdx.x * 256;
    const int d  = d0 + tid;
    const int c = blockIdx.y;
    const int b = blockIdx.z;
    const int t0 = c * LC;

    for (int i = tid; i < LC * NST; i += 256) {
        const size_t row = (size_t)(b * LSEQ + t0 + (i >> 4)) * 96;
        sB[i >> 4][i & 15] = xdbl[row + 64 + (i & 15)];
        sC[i >> 4][i & 15] = xdbl[row + 80 + (i & 15)];
    }

    float Av[NST], h[NST];
#pragma unroll
    for (int n = 0; n < NST; ++n)
        Av[n] = -__expf(A_log[d * NST + n]) * 1.44269504f;

    const size_t hbase = ((size_t)(b * CH + c) * DI + d) * NST;
#pragma unroll
    for (int n = 0; n < NST; n += 4) {
        f32x4 t = *(const f32x4*)&hin[hbase + n];
        h[n] = t.x; h[n+1] = t.y; h[n+2] = t.z; h[n+3] = t.w;
    }
    const float Dskv = Dskip[d];

    const float*          dbase = delta + (size_t)(b * LSEQ + t0) * DI + d0;
    const unsigned short* ubase = ub    + (size_t)(b * LSEQ + t0) * DI + d0;
    const unsigned short* zbase = xzb   + (size_t)(b * LSEQ + t0) * (2 * DI) + DI + d0;
    unsigned short* yrow = yg + (size_t)(b * LSEQ + t0) * DI + d;

    for (int sub = 0; sub < LC; sub += 8) {
        __syncthreads();
#pragma unroll
        for (int it = 0; it < 2; ++it) {
            const int slot = tid + it * 256;
            const int tt = slot >> 6, dq = (slot & 63) * 4;
            *(float4*)&s_d[tt][dq] = *(const float4*)(dbase + (size_t)(sub + tt) * DI + dq);
        }
        {
            const int tt = tid >> 5, d8 = (tid & 31) * 8;
            *(short8*)&s_u[tt][d8] = *(const short8*)(ubase + (size_t)(sub + tt) * DI + d8);
            *(short8*)&s_z[tt][d8] = *(const short8*)(zbase + (size_t)(sub + tt) * (2 * DI) + d8);
        }
        __syncthreads();
#pragma unroll
        for (int q = 0; q < 8; ++q) {
            const float dlt = s_d[q][tid];
            const float uu  = bf2f(s_u[q][tid]);
            const float du  = dlt * uu;
            float y = 0.f;
#pragma unroll
            for (int n = 0; n < NST; ++n) {
                const float dA = __builtin_amdgcn_exp2f(dlt * Av[n]);
                h[n] = fmaf(dA, h[n], du * sB[sub + q][n]);
                y = fmaf(h[n], sC[sub + q][n], y);
            }
            const float zv = bf2f(s_z[q][tid]);
            const float sig = __frcp_rn(1.f + __expf(-zv));
            const float val = (y + uu * Dskv) * (zv * sig);
            yrow[(size_t)(sub + q) * DI] = f2bf(val);
        }
    }
}

// ---------------------------------------------------------------------------
extern "C" void kernel_launch(void* const* d_in, const int* in_sizes, int n_in,
                              void* d_out, int out_size, void* d_ws, size_t ws_size,
                              hipStream_t stream)
{
    const float* x        = (const float*)d_in[0];
    const float* in_w     = (const float*)d_in[1];
    const float* conv_w   = (const float*)d_in[2];
    const float* conv_b   = (const float*)d_in[3];
    const float* xproj_w  = (const float*)d_in[4];
    const float* dtproj_w = (const float*)d_in[5];
    const float* dtproj_b = (const float*)d_in[6];
    const float* A_log    = (const float*)d_in[7];
    const float* Dskip    = (const float*)d_in[8];
    const float* out_w    = (const float*)d_in[9];
    float* out = (float*)d_out;

    char* ws = (char*)d_ws;
#define MB(x) ((size_t)(x) * 1024 * 1024)
    unsigned short* xzb   = (unsigned short*)(ws);           // bf16 [4096,4096] 32 MB
    unsigned short* ub    = (unsigned short*)(ws + MB(32));  // bf16 [4096,2048] 16 MB
    float*          delta = (float*)(ws + MB(48));           // fp32 [4096,2048] 32 MB
    float*          xdbl  = (float*)(ws + MB(80));           // fp32 [4096,96]  1.5 MB
    unsigned short* ygb   = (unsigned short*)(ws + MB(82));  // bf16 [4096,2048] 16 MB
    float*          P     = (float*)(ws + MB(98));           // 16 MB (also x_proj partials)
    float*          S     = (float*)(ws + MB(114));          // 16 MB
    float*          hin   = (float*)(ws + MB(130));          // 16 MB
    unsigned short* xb    = (unsigned short*)(ws + MB(146)); // bf16 x      8 MB
    unsigned short* wb1   = (unsigned short*)(ws + MB(154)); // bf16 in_w   8 MB
    unsigned short* wb3   = (unsigned short*)(ws + MB(162)); // bf16 xproj  0.4 MB
    unsigned short* wb6   = (unsigned short*)(ws + MB(163)); // bf16 out_w  4 MB
    float*          xdbl_part = P;                           // 8 x [4096,96]

    dim3 blk(256);

    cast_bf16<<<dim3((BLTOK * DM / 4 + 255) / 256), blk, 0, stream>>>(x, xb, BLTOK * DM / 4);
    cast_bf16<<<dim3((2 * DI * DM / 4 + 255) / 256), blk, 0, stream>>>(in_w, wb1, 2 * DI * DM / 4);
    cast_bf16<<<dim3((96 * DI / 4 + 255) / 256), blk, 0, stream>>>(xproj_w, wb3, 96 * DI / 4);
    cast_bf16<<<dim3((DM * DI / 4 + 255) / 256), blk, 0, stream>>>(out_w, wb6, DM * DI / 4);

    // 1) in_proj: xzb = bf16(x @ in_w^T)   [4096 x 4096], K=1024
    gemm_db<1><<<dim3(32, 32), blk, 0, stream>>>(xb, wb1, xzb, BLTOK, 2 * DI, DM, DM, DM, 2 * DI);

    // 2) conv + silu -> ub (bf16)
    conv_silu_kernel<<<dim3(BLTOK), blk, 0, stream>>>(xzb, conv_w, conv_b, ub);

    // 3) x_proj split-K=8: partials then reduce   [4096 x 96], K=2048
    gemm_mfma_sk<<<dim3(1, 32, 8), blk, 0, stream>>>(ub, wb3, xdbl_part,
                                                     BLTOK, DTR + 2 * NST, DI, DI, DI, 96, 8);
    sk_reduce<<<dim3((BLTOK * 96 / 4 + 255) / 256), blk, 0, stream>>>(xdbl_part, xdbl,
                                                                      BLTOK * 96 / 4, 8);

    // 4) dt_proj + softplus (fp32, K=64)
    gemm_bt_sp<<<dim3(16, 32), blk, 0, stream>>>(xdbl, dtproj_w, delta, dtproj_b,
                                                 BLTOK, DI, DTR, 96, DTR, DI);

    // 5) chunked selective scan
    scan_phase1<<<dim3(DI / 256, CH, NB), blk, 0, stream>>>(delta, ub, xdbl, A_log, P, S);
    scan_phase2<<<dim3(NB * DI * NST / 256), blk, 0, stream>>>(P, S, hin);
    scan_phase3<<<dim3(DI / 256, CH, NB), blk, 0, stream>>>(delta, ub, xdbl, A_log, Dskip,
                                                            xzb, hin, ygb);

    // 6) out_proj: out = yg @ out_w^T   [4096 x 1024], K=2048
    gemm_db<0><<<dim3(8, 32), blk, 0, stream>>>(ygb, wb6, out, BLTOK, DM, DI, DI, DI, DM);
}

// Round 5
// 263.354 us; speedup vs baseline: 6.3712x; 1.0546x over previous
//
#include <hip/hip_runtime.h>
#include <hip/hip_bf16.h>
#include <math.h>

// Problem constants (MambaBlock: D_MODEL=1024, D_STATE=16, D_CONV=4, EXPAND=2, DT_RANK=64)
#define NB      2
#define LSEQ    2048
#define BLTOK   4096      // NB * LSEQ
#define DM      1024
#define DI      2048      // EXPAND * DM
#define NST     16
#define DTR     64
#define CH      64        // scan chunks
#define LC      32        // LSEQ / CH

typedef __attribute__((ext_vector_type(8))) short short8;
typedef __attribute__((ext_vector_type(4))) float f32x4;

#define LDS_PTR(p) ((__attribute__((address_space(3))) void*)(p))
#define GLB_PTR(p) ((const __attribute__((address_space(1))) void*)(p))

static __device__ __forceinline__ unsigned short f2bf(float f) {
    unsigned int u = __float_as_uint(f);
    unsigned int r = (u + 0x7FFFu + ((u >> 16) & 1u)) >> 16;   // RNE
    return (unsigned short)r;
}
static __device__ __forceinline__ float bf2f(unsigned short v) {
    return __uint_as_float((unsigned int)v << 16);
}

// ---------------------------------------------------------------------------
// fp32 -> bf16 cast (vector)
// ---------------------------------------------------------------------------
__launch_bounds__(256)
__global__ void cast_bf16(const float* __restrict__ in, unsigned short* __restrict__ out, int n4)
{
    int i = blockIdx.x * 256 + threadIdx.x;
    if (i < n4) {
        float4 v = ((const float4*)in)[i];
        uint2 o;
        o.x = (unsigned)f2bf(v.x) | ((unsigned)f2bf(v.y) << 16);
        o.y = (unsigned)f2bf(v.z) | ((unsigned)f2bf(v.w) << 16);
        ((uint2*)out)[i] = o;
    }
}

// ---------------------------------------------------------------------------
// bf16 MFMA GEMM, BK=64 double-buffered 2-phase pipeline.
// LDS XOR swizzle (both-sides): 16B slot s within each 128B row holds global
// slot s ^ (row&7); reads XOR the same term.
// M,N multiples of 128, K multiple of 64.
// EPI 0: fp32 C.  EPI 1: bf16 C.  EPI 2: fp32 softplus(acc + bias[col]).
// ---------------------------------------------------------------------------
template<int EPI>
__launch_bounds__(256)
__global__ void gemm_db(const unsigned short* __restrict__ A,
                        const unsigned short* __restrict__ W,
                        void* __restrict__ Cout,
                        const float* __restrict__ bias,
                        int M, int N, int K, int lda, int ldb, int ldc)
{
    __shared__ unsigned short lds[2][2][128 * 64];   // 64 KB

    const int tid = threadIdx.x;
    const int l = tid & 63;
    const int w = tid >> 6;
    const int wr = w >> 1, wc = w & 1;
    const int brow = blockIdx.y * 128;
    const int bcol = blockIdx.x * 128;

    const int strow = tid >> 3;                          // 0..31
    const int scol  = ((tid & 7) ^ (strow & 7)) * 8;     // swizzled source col

    f32x4 acc[4][4];
#pragma unroll
    for (int i = 0; i < 4; ++i)
#pragma unroll
        for (int j = 0; j < 4; ++j) acc[i][j] = (f32x4)0.f;

    auto stage = [&](int bb, int k0) {
#pragma unroll
        for (int i = 0; i < 4; ++i) {
            const unsigned short* ga = A + (size_t)(brow + i * 32 + strow) * lda + k0 + scol;
            __builtin_amdgcn_global_load_lds(GLB_PTR(ga),
                LDS_PTR((char*)&lds[bb][0][0] + (i * 32 + w * 8) * 128), 16, 0, 0);
            const unsigned short* gb = W + (size_t)(bcol + i * 32 + strow) * ldb + k0 + scol;
            __builtin_amdgcn_global_load_lds(GLB_PTR(gb),
                LDS_PTR((char*)&lds[bb][1][0] + (i * 32 + w * 8) * 128), 16, 0, 0);
        }
    };

    auto compute = [&](int bb) {
        const char* baseA = (const char*)&lds[bb][0][0];
        const char* baseB = (const char*)&lds[bb][1][0];
        const int xo  = (l & 7) * 16;
        const int ko0 = (l >> 4) * 16;
#pragma unroll
        for (int ks = 0; ks < 2; ++ks) {
            const int kb = ks * 64 + ko0;
            short8 af[4], bfr[4];
#pragma unroll
            for (int i = 0; i < 4; ++i) {
                const int rowA = wr * 64 + i * 16 + (l & 15);
                af[i] = *(const short8*)(baseA + rowA * 128 + (kb ^ xo));
                const int rowB = wc * 64 + i * 16 + (l & 15);
                bfr[i] = *(const short8*)(baseB + rowB * 128 + (kb ^ xo));
            }
#pragma unroll
            for (int i = 0; i < 4; ++i)
#pragma unroll
                for (int j = 0; j < 4; ++j)
                    acc[i][j] = __builtin_amdgcn_mfma_f32_16x16x32_bf16(af[i], bfr[j], acc[i][j], 0, 0, 0);
        }
    };

    const int nt = K / 64;
    stage(0, 0);
    __syncthreads();
    int cur = 0;
    for (int t = 0; t < nt - 1; ++t) {
        stage(cur ^ 1, (t + 1) * 64);
        compute(cur);
        __syncthreads();
        cur ^= 1;
    }
    compute(cur);

#pragma unroll
    for (int i = 0; i < 4; ++i) {
        const int row0 = brow + wr * 64 + i * 16 + ((l >> 4) * 4);
#pragma unroll
        for (int j = 0; j < 4; ++j) {
            const int col = bcol + wc * 64 + j * 16 + (l & 15);
            if (EPI == 1) {
                unsigned short* Cb = (unsigned short*)Cout;
#pragma unroll
                for (int r = 0; r < 4; ++r)
                    Cb[(size_t)(row0 + r) * ldc + col] = f2bf(acc[i][j][r]);
            } else if (EPI == 2) {
                float* Cf = (float*)Cout;
                const float bv = bias[col];
#pragma unroll
                for (int r = 0; r < 4; ++r) {
                    float v = acc[i][j][r] + bv;
                    Cf[(size_t)(row0 + r) * ldc + col] = (v > 20.f) ? v : log1pf(__expf(v));
                }
            } else {
                float* Cf = (float*)Cout;
#pragma unroll
                for (int r = 0; r < 4; ++r)
                    Cf[(size_t)(row0 + r) * ldc + col] = acc[i][j][r];
            }
        }
    }
}

// ---------------------------------------------------------------------------
// Split-K MFMA GEMM for x_proj (N=96): blockIdx.z = k-slice, partial C out.
// ---------------------------------------------------------------------------
__launch_bounds__(256)
__global__ void gemm_mfma_sk(const unsigned short* __restrict__ A,
                             const unsigned short* __restrict__ W,
                             float* __restrict__ Cpart,
                             int M, int N, int K, int lda, int ldb, int ldc, int kslices)
{
    __shared__ unsigned short Asub[128 * 32];
    __shared__ unsigned short Bsub[128 * 32];

    const int tid = threadIdx.x;
    const int l = tid & 63;
    const int w = tid >> 6;
    const int wr = w >> 1, wc = w & 1;
    const int brow = blockIdx.y * 128;
    const int bcol = blockIdx.x * 128;
    const int ks = blockIdx.z;
    const int klen = K / kslices;
    const int kbeg = ks * klen;
    float* C = Cpart + (size_t)ks * M * ldc;

    f32x4 acc[4][4];
#pragma unroll
    for (int i = 0; i < 4; ++i)
#pragma unroll
        for (int j = 0; j < 4; ++j) acc[i][j] = (f32x4)0.f;

    const int srow = tid >> 2;
    const int scol = (tid & 3) * 8;

    for (int k0 = kbeg; k0 < kbeg + klen; k0 += 32) {
#pragma unroll
        for (int i = 0; i < 2; ++i) {
            const int ar = brow + i * 64 + srow;
            const unsigned short* ga = A + (size_t)ar * lda + k0 + scol;
            __builtin_amdgcn_global_load_lds(GLB_PTR(ga),
                LDS_PTR((char*)Asub + i * 4096 + w * 1024), 16, 0, 0);
            int nr = bcol + i * 64 + srow;
            if (nr > N - 1) nr = N - 1;
            const unsigned short* gb = W + (size_t)nr * ldb + k0 + scol;
            __builtin_amdgcn_global_load_lds(GLB_PTR(gb),
                LDS_PTR((char*)Bsub + i * 4096 + w * 1024), 16, 0, 0);
        }
        __syncthreads();

        short8 af[4], bf[4];
#pragma unroll
        for (int i = 0; i < 4; ++i) {
            const int row = wr * 64 + i * 16 + (l & 15);
            af[i] = *(const short8*)((const char*)Asub + row * 64 + (l >> 4) * 16);
        }
#pragma unroll
        for (int j = 0; j < 4; ++j) {
            const int row = wc * 64 + j * 16 + (l & 15);
            bf[j] = *(const short8*)((const char*)Bsub + row * 64 + (l >> 4) * 16);
        }
#pragma unroll
        for (int i = 0; i < 4; ++i)
#pragma unroll
            for (int j = 0; j < 4; ++j)
                acc[i][j] = __builtin_amdgcn_mfma_f32_16x16x32_bf16(af[i], bf[j], acc[i][j], 0, 0, 0);
        __syncthreads();
    }

#pragma unroll
    for (int i = 0; i < 4; ++i) {
        const int row0 = brow + wr * 64 + i * 16 + ((l >> 4) * 4);
#pragma unroll
        for (int j = 0; j < 4; ++j) {
            const int col = bcol + wc * 64 + j * 16 + (l & 15);
            if (col < N) {
#pragma unroll
                for (int r = 0; r < 4; ++r)
                    C[(size_t)(row0 + r) * ldc + col] = acc[i][j][r];
            }
        }
    }
}

// sum partial slices -> xdbl (fp32) + compact bf16 copy of dt cols [0,64)
__launch_bounds__(256)
__global__ void sk_reduce(const float* __restrict__ part, float* __restrict__ out,
                          unsigned short* __restrict__ dtb, int n4, int slices)
{
    int i = blockIdx.x * 256 + threadIdx.x;
    if (i < n4) {
        float4 s = ((const float4*)part)[i];
        for (int k = 1; k < slices; ++k) {
            float4 p = ((const float4*)part)[(size_t)k * n4 + i];
            s.x += p.x; s.y += p.y; s.z += p.z; s.w += p.w;
        }
        ((float4*)out)[i] = s;
        const int r = i / 24, cq = i % 24;          // row, float4-slot within 96-col row
        if (cq < 16) {                               // cols 4*cq..4*cq+3 < 64 (dt)
            uint2 o;
            o.x = (unsigned)f2bf(s.x) | ((unsigned)f2bf(s.y) << 16);
            o.y = (unsigned)f2bf(s.z) | ((unsigned)f2bf(s.w) << 16);
            *(uint2*)&dtb[(size_t)r * DTR + cq * 4] = o;
        }
    }
}

// ---------------------------------------------------------------------------
// Causal depthwise conv1d (width 4) + bias + silu.  bf16 in/out.
// ---------------------------------------------------------------------------
__launch_bounds__(256)
__global__ void conv_silu_kernel(const unsigned short* __restrict__ xzb,
                                 const float* __restrict__ cw,
                                 const float* __restrict__ cb,
                                 unsigned short* __restrict__ ub)
{
    const int orig = blockIdx.x;
    const int bl = (orig & 7) * (BLTOK / 8) + (orig >> 3);   // bijective (4096%8==0)
    const int l  = bl & (LSEQ - 1);
    const int d0 = threadIdx.x * 8;

    float acc[8];
    float4 w4[8];
#pragma unroll
    for (int q = 0; q < 8; ++q) {
        w4[q]  = *(const float4*)&cw[(d0 + q) * 4];
        acc[q] = cb[d0 + q];
    }
#pragma unroll
    for (int k = 0; k < 4; ++k) {
        const int ls = l - 3 + k;
        if (ls < 0) continue;
        short8 v = *(const short8*)&xzb[(size_t)(bl - 3 + k) * (2 * DI) + d0];
#pragma unroll
        for (int q = 0; q < 8; ++q) {
            const float wk = ((const float*)&w4[q])[k];
            acc[q] = fmaf(wk, bf2f((unsigned short)v[q]), acc[q]);
        }
    }
    short8 o;
#pragma unroll
    for (int q = 0; q < 8; ++q) {
        const float s = acc[q] / (1.f + __expf(-acc[q]));
        o[q] = (short)f2bf(s);
    }
    *(short8*)&ub[(size_t)bl * DI + d0] = o;
}

// ---------------------------------------------------------------------------
// Scan phase 1: per chunk, per (b,d): 16 n-states in registers.
// ---------------------------------------------------------------------------
__launch_bounds__(256)
__global__ void scan_phase1(const float* __restrict__ delta, const unsigned short* __restrict__ ub,
                            const float* __restrict__ xdbl, const float* __restrict__ A_log,
                            float* __restrict__ P, float* __restrict__ S)
{
    __shared__ float s_d[8][256];
    __shared__ unsigned short s_u[8][256];
    __shared__ float sB[LC][NST];
    const int tid = threadIdx.x;
    const int d0 = blockIdx.x * 256;
    const int d  = d0 + tid;
    const int c = blockIdx.y;
    const int b = blockIdx.z;
    const int t0 = c * LC;

    for (int i = tid; i < LC * NST; i += 256)
        sB[i >> 4][i & 15] = xdbl[(size_t)(b * LSEQ + t0 + (i >> 4)) * 96 + 64 + (i & 15)];

    float Av[NST], Pv[NST], Sv[NST];
#pragma unroll
    for (int n = 0; n < NST; ++n) {
        Av[n] = -__expf(A_log[d * NST + n]) * 1.44269504f;
        Pv[n] = 1.f; Sv[n] = 0.f;
    }

    const float*          dbase = delta + (size_t)(b * LSEQ + t0) * DI + d0;
    const unsigned short* ubase = ub    + (size_t)(b * LSEQ + t0) * DI + d0;

    for (int sub = 0; sub < LC; sub += 8) {
        __syncthreads();
#pragma unroll
        for (int it = 0; it < 2; ++it) {
            const int slot = tid + it * 256;
            const int tt = slot >> 6, dq = (slot & 63) * 4;
            *(float4*)&s_d[tt][dq] = *(const float4*)(dbase + (size_t)(sub + tt) * DI + dq);
        }
        {
            const int tt = tid >> 5, d8 = (tid & 31) * 8;
            *(short8*)&s_u[tt][d8] = *(const short8*)(ubase + (size_t)(sub + tt) * DI + d8);
        }
        __syncthreads();
#pragma unroll
        for (int q = 0; q < 8; ++q) {
            const float dlt = s_d[q][tid];
            const float uu  = bf2f(s_u[q][tid]);
            const float du  = dlt * uu;
#pragma unroll
            for (int n = 0; n < NST; ++n) {
                const float dA = __builtin_amdgcn_exp2f(dlt * Av[n]);
                Pv[n] *= dA;
                Sv[n] = fmaf(dA, Sv[n], du * sB[sub + q][n]);
            }
        }
    }

    const size_t base = ((size_t)(b * CH + c) * DI + d) * NST;
#pragma unroll
    for (int n = 0; n < NST; n += 4) {
        *(f32x4*)&P[base + n] = (f32x4){Pv[n], Pv[n+1], Pv[n+2], Pv[n+3]};
        *(f32x4*)&S[base + n] = (f32x4){Sv[n], Sv[n+1], Sv[n+2], Sv[n+3]};
    }
}

// ---------------------------------------------------------------------------
// Scan phase 2: sequential combine over chunks.
// ---------------------------------------------------------------------------
__launch_bounds__(256)
__global__ void scan_phase2(const float* __restrict__ P, const float* __restrict__ S,
                            float* __restrict__ hin)
{
    const int g = blockIdx.x * 256 + threadIdx.x;
    const int n = g & 15;
    const int d = (g >> 4) & (DI - 1);
    const int b = g >> 15;
    float h = 0.f;
#pragma unroll 4
    for (int c = 0; c < CH; ++c) {
        const size_t idx = ((size_t)(b * CH + c) * DI + d) * NST + n;
        hin[idx] = h;
        h = fmaf(P[idx], h, S[idx]);
    }
}

// ---------------------------------------------------------------------------
// Scan phase 3: replay chunk with h_in; fuse D-skip + silu(z) gating; bf16 out.
// ---------------------------------------------------------------------------
__launch_bounds__(256)
__global__ void scan_phase3(const float* __restrict__ delta, const unsigned short* __restrict__ ub,
                            const float* __restrict__ xdbl, const float* __restrict__ A_log,
                            const float* __restrict__ Dskip, const unsigned short* __restrict__ xzb,
                            const float* __restrict__ hin, unsigned short* __restrict__ yg)
{
    __shared__ float s_d[8][256];
    __shared__ unsigned short s_u[8][256], s_z[8][256];
    __shared__ float sB[LC][NST], sC[LC][NST];
    const int tid = threadIdx.x;
    const int d0 = blockIdx.x * 256;
    const int d  = d0 + tid;
    const int c = blockIdx.y;
    const int b = blockIdx.z;
    const int t0 = c * LC;

    for (int i = tid; i < LC * NST; i += 256) {
        const size_t row = (size_t)(b * LSEQ + t0 + (i >> 4)) * 96;
        sB[i >> 4][i & 15] = xdbl[row + 64 + (i & 15)];
        sC[i >> 4][i & 15] = xdbl[row + 80 + (i & 15)];
    }

    float Av[NST], h[NST];
#pragma unroll
    for (int n = 0; n < NST; ++n)
        Av[n] = -__expf(A_log[d * NST + n]) * 1.44269504f;

    const size_t hbase = ((size_t)(b * CH + c) * DI + d) * NST;
#pragma unroll
    for (int n = 0; n < NST; n += 4) {
        f32x4 t = *(const f32x4*)&hin[hbase + n];
        h[n] = t.x; h[n+1] = t.y; h[n+2] = t.z; h[n+3] = t.w;
    }
    const float Dskv = Dskip[d];

    const float*          dbase = delta + (size_t)(b * LSEQ + t0) * DI + d0;
    const unsigned short* ubase = ub    + (size_t)(b * LSEQ + t0) * DI + d0;
    const unsigned short* zbase = xzb   + (size_t)(b * LSEQ + t0) * (2 * DI) + DI + d0;
    unsigned short* yrow = yg + (size_t)(b * LSEQ + t0) * DI + d;

    for (int sub = 0; sub < LC; sub += 8) {
        __syncthreads();
#pragma unroll
        for (int it = 0; it < 2; ++it) {
            const int slot = tid + it * 256;
            const int tt = slot >> 6, dq = (slot & 63) * 4;
            *(float4*)&s_d[tt][dq] = *(const float4*)(dbase + (size_t)(sub + tt) * DI + dq);
        }
        {
            const int tt = tid >> 5, d8 = (tid & 31) * 8;
            *(short8*)&s_u[tt][d8] = *(const short8*)(ubase + (size_t)(sub + tt) * DI + d8);
            *(short8*)&s_z[tt][d8] = *(const short8*)(zbase + (size_t)(sub + tt) * (2 * DI) + d8);
        }
        __syncthreads();
#pragma unroll
        for (int q = 0; q < 8; ++q) {
            const float dlt = s_d[q][tid];
            const float uu  = bf2f(s_u[q][tid]);
            const float du  = dlt * uu;
            float y = 0.f;
#pragma unroll
            for (int n = 0; n < NST; ++n) {
                const float dA = __builtin_amdgcn_exp2f(dlt * Av[n]);
                h[n] = fmaf(dA, h[n], du * sB[sub + q][n]);
                y = fmaf(h[n], sC[sub + q][n], y);
            }
            const float zv = bf2f(s_z[q][tid]);
            const float sig = __frcp_rn(1.f + __expf(-zv));
            const float val = (y + uu * Dskv) * (zv * sig);
            yrow[(size_t)(sub + q) * DI] = f2bf(val);
        }
    }
}

// ---------------------------------------------------------------------------
extern "C" void kernel_launch(void* const* d_in, const int* in_sizes, int n_in,
                              void* d_out, int out_size, void* d_ws, size_t ws_size,
                              hipStream_t stream)
{
    const float* x        = (const float*)d_in[0];
    const float* in_w     = (const float*)d_in[1];
    const float* conv_w   = (const float*)d_in[2];
    const float* conv_b   = (const float*)d_in[3];
    const float* xproj_w  = (const float*)d_in[4];
    const float* dtproj_w = (const float*)d_in[5];
    const float* dtproj_b = (const float*)d_in[6];
    const float* A_log    = (const float*)d_in[7];
    const float* Dskip    = (const float*)d_in[8];
    const float* out_w    = (const float*)d_in[9];
    float* out = (float*)d_out;

    char* ws = (char*)d_ws;
#define MB(x) ((size_t)(x) * 1024 * 1024)
    unsigned short* xzb   = (unsigned short*)(ws);           // bf16 [4096,4096] 32 MB
    unsigned short* ub    = (unsigned short*)(ws + MB(32));  // bf16 [4096,2048] 16 MB
    float*          delta = (float*)(ws + MB(48));           // fp32 [4096,2048] 32 MB
    float*          xdbl  = (float*)(ws + MB(80));           // fp32 [4096,96]  1.5 MB
    unsigned short* ygb   = (unsigned short*)(ws + MB(82));  // bf16 [4096,2048] 16 MB
    float*          P     = (float*)(ws + MB(98));           // 16 MB (also x_proj partials)
    float*          S     = (float*)(ws + MB(114));          // 16 MB
    float*          hin   = (float*)(ws + MB(130));          // 16 MB
    unsigned short* xb    = (unsigned short*)(ws + MB(146)); // bf16 x      8 MB
    unsigned short* wb1   = (unsigned short*)(ws + MB(154)); // bf16 in_w   8 MB
    unsigned short* wb3   = (unsigned short*)(ws + MB(162)); // bf16 xproj  0.4 MB
    unsigned short* wb6   = (unsigned short*)(ws + MB(163)); // bf16 out_w  4 MB
    unsigned short* wb5   = (unsigned short*)(ws + MB(167)); // bf16 dtproj_w 0.25 MB
    unsigned short* dtb   = (unsigned short*)(ws + MB(168)); // bf16 dt [4096,64] 0.5 MB
    float*          xdbl_part = P;                           // 8 x [4096,96]

    dim3 blk(256);

    cast_bf16<<<dim3((BLTOK * DM / 4 + 255) / 256), blk, 0, stream>>>(x, xb, BLTOK * DM / 4);
    cast_bf16<<<dim3((2 * DI * DM / 4 + 255) / 256), blk, 0, stream>>>(in_w, wb1, 2 * DI * DM / 4);
    cast_bf16<<<dim3((96 * DI / 4 + 255) / 256), blk, 0, stream>>>(xproj_w, wb3, 96 * DI / 4);
    cast_bf16<<<dim3((DM * DI / 4 + 255) / 256), blk, 0, stream>>>(out_w, wb6, DM * DI / 4);
    cast_bf16<<<dim3((DI * DTR / 4 + 255) / 256), blk, 0, stream>>>(dtproj_w, wb5, DI * DTR / 4);

    // 1) in_proj: xzb = bf16(x @ in_w^T)   [4096 x 4096], K=1024
    gemm_db<1><<<dim3(32, 32), blk, 0, stream>>>(xb, wb1, xzb, nullptr,
                                                 BLTOK, 2 * DI, DM, DM, DM, 2 * DI);

    // 2) conv + silu -> ub (bf16)
    conv_silu_kernel<<<dim3(BLTOK), blk, 0, stream>>>(xzb, conv_w, conv_b, ub);

    // 3) x_proj split-K=8: partials then reduce (fp32 xdbl + bf16 dt copy)
    gemm_mfma_sk<<<dim3(1, 32, 8), blk, 0, stream>>>(ub, wb3, xdbl_part,
                                                     BLTOK, DTR + 2 * NST, DI, DI, DI, 96, 8);
    sk_reduce<<<dim3((BLTOK * 96 / 4 + 255) / 256), blk, 0, stream>>>(xdbl_part, xdbl, dtb,
                                                                      BLTOK * 96 / 4, 8);

    // 4) dt_proj + softplus: delta = softplus(dtb @ wb5^T + b)  [4096 x 2048], K=64 (MFMA)
    gemm_db<2><<<dim3(16, 32), blk, 0, stream>>>(dtb, wb5, delta, dtproj_b,
                                                 BLTOK, DI, DTR, DTR, DTR, DI);

    // 5) chunked selective scan
    scan_phase1<<<dim3(DI / 256, CH, NB), blk, 0, stream>>>(delta, ub, xdbl, A_log, P, S);
    scan_phase2<<<dim3(NB * DI * NST / 256), blk, 0, stream>>>(P, S, hin);
    scan_phase3<<<dim3(DI / 256, CH, NB), blk, 0, stream>>>(delta, ub, xdbl, A_log, Dskip,
                                                            xzb, hin, ygb);

    // 6) out_proj: out = yg @ out_w^T   [4096 x 1024], K=2048
    gemm_db<0><<<dim3(8, 32), blk, 0, stream>>>(ygb, wb6, out, nullptr,
                                                BLTOK, DM, DI, DI, DI, DM);
}

// Round 6
// 254.649 us; speedup vs baseline: 6.5890x; 1.0342x over previous
//
#include <hip/hip_runtime.h>
#include <hip/hip_bf16.h>
#include <math.h>

// Problem constants (MambaBlock: D_MODEL=1024, D_STATE=16, D_CONV=4, EXPAND=2, DT_RANK=64)
#define NB      2
#define LSEQ    2048
#define BLTOK   4096      // NB * LSEQ
#define DM      1024
#define DI      2048      // EXPAND * DM
#define NST     16
#define DTR     64
#define CH      128       // scan chunks
#define LC      16        // LSEQ / CH
#define LOG2E   1.44269504f

typedef __attribute__((ext_vector_type(8))) short short8;
typedef __attribute__((ext_vector_type(4))) float f32x4;

#define LDS_PTR(p) ((__attribute__((address_space(3))) void*)(p))
#define GLB_PTR(p) ((const __attribute__((address_space(1))) void*)(p))

static __device__ __forceinline__ unsigned short f2bf(float f) {
    unsigned int u = __float_as_uint(f);
    unsigned int r = (u + 0x7FFFu + ((u >> 16) & 1u)) >> 16;   // RNE
    return (unsigned short)r;
}
static __device__ __forceinline__ float bf2f(unsigned short v) {
    return __uint_as_float((unsigned int)v << 16);
}

// w^(n+1) for n=0..15 via binary tree (depth 4, 15 full-rate muls)
static __device__ __forceinline__ void pow_tree(float w, float* e) {
    e[0]  = w;
    e[1]  = e[0] * e[0];
    e[2]  = e[1] * e[0];
    e[3]  = e[1] * e[1];
    e[4]  = e[3] * e[0];
    e[5]  = e[3] * e[1];
    e[6]  = e[3] * e[2];
    e[7]  = e[3] * e[3];
    e[8]  = e[7] * e[0];
    e[9]  = e[7] * e[1];
    e[10] = e[7] * e[2];
    e[11] = e[7] * e[3];
    e[12] = e[7] * e[4];
    e[13] = e[7] * e[5];
    e[14] = e[7] * e[6];
    e[15] = e[7] * e[7];
}

// ---------------------------------------------------------------------------
// fp32 -> bf16 cast (vector)
// ---------------------------------------------------------------------------
__launch_bounds__(256)
__global__ void cast_bf16(const float* __restrict__ in, unsigned short* __restrict__ out, int n4)
{
    int i = blockIdx.x * 256 + threadIdx.x;
    if (i < n4) {
        float4 v = ((const float4*)in)[i];
        uint2 o;
        o.x = (unsigned)f2bf(v.x) | ((unsigned)f2bf(v.y) << 16);
        o.y = (unsigned)f2bf(v.z) | ((unsigned)f2bf(v.w) << 16);
        ((uint2*)out)[i] = o;
    }
}

// ---------------------------------------------------------------------------
// bf16 MFMA GEMM, BK=64 double-buffered 2-phase pipeline.
// LDS XOR swizzle (both-sides). M,N mult of 128, K mult of 64.
// EPI 0: fp32 C.  EPI 1: bf16 C.  EPI 2: fp32 softplus(acc + bias[col]).
// ---------------------------------------------------------------------------
template<int EPI>
__launch_bounds__(256)
__global__ void gemm_db(const unsigned short* __restrict__ A,
                        const unsigned short* __restrict__ W,
                        void* __restrict__ Cout,
                        const float* __restrict__ bias,
                        int M, int N, int K, int lda, int ldb, int ldc)
{
    __shared__ unsigned short lds[2][2][128 * 64];   // 64 KB

    const int tid = threadIdx.x;
    const int l = tid & 63;
    const int w = tid >> 6;
    const int wr = w >> 1, wc = w & 1;
    const int brow = blockIdx.y * 128;
    const int bcol = blockIdx.x * 128;

    const int strow = tid >> 3;                          // 0..31
    const int scol  = ((tid & 7) ^ (strow & 7)) * 8;     // swizzled source col

    f32x4 acc[4][4];
#pragma unroll
    for (int i = 0; i < 4; ++i)
#pragma unroll
        for (int j = 0; j < 4; ++j) acc[i][j] = (f32x4)0.f;

    auto stage = [&](int bb, int k0) {
#pragma unroll
        for (int i = 0; i < 4; ++i) {
            const unsigned short* ga = A + (size_t)(brow + i * 32 + strow) * lda + k0 + scol;
            __builtin_amdgcn_global_load_lds(GLB_PTR(ga),
                LDS_PTR((char*)&lds[bb][0][0] + (i * 32 + w * 8) * 128), 16, 0, 0);
            const unsigned short* gb = W + (size_t)(bcol + i * 32 + strow) * ldb + k0 + scol;
            __builtin_amdgcn_global_load_lds(GLB_PTR(gb),
                LDS_PTR((char*)&lds[bb][1][0] + (i * 32 + w * 8) * 128), 16, 0, 0);
        }
    };

    auto compute = [&](int bb) {
        const char* baseA = (const char*)&lds[bb][0][0];
        const char* baseB = (const char*)&lds[bb][1][0];
        const int xo  = (l & 7) * 16;
        const int ko0 = (l >> 4) * 16;
#pragma unroll
        for (int ks = 0; ks < 2; ++ks) {
            const int kb = ks * 64 + ko0;
            short8 af[4], bfr[4];
#pragma unroll
            for (int i = 0; i < 4; ++i) {
                const int rowA = wr * 64 + i * 16 + (l & 15);
                af[i] = *(const short8*)(baseA + rowA * 128 + (kb ^ xo));
                const int rowB = wc * 64 + i * 16 + (l & 15);
                bfr[i] = *(const short8*)(baseB + rowB * 128 + (kb ^ xo));
            }
#pragma unroll
            for (int i = 0; i < 4; ++i)
#pragma unroll
                for (int j = 0; j < 4; ++j)
                    acc[i][j] = __builtin_amdgcn_mfma_f32_16x16x32_bf16(af[i], bfr[j], acc[i][j], 0, 0, 0);
        }
    };

    const int nt = K / 64;
    stage(0, 0);
    __syncthreads();
    int cur = 0;
    for (int t = 0; t < nt - 1; ++t) {
        stage(cur ^ 1, (t + 1) * 64);
        compute(cur);
        __syncthreads();
        cur ^= 1;
    }
    compute(cur);

#pragma unroll
    for (int i = 0; i < 4; ++i) {
        const int row0 = brow + wr * 64 + i * 16 + ((l >> 4) * 4);
#pragma unroll
        for (int j = 0; j < 4; ++j) {
            const int col = bcol + wc * 64 + j * 16 + (l & 15);
            if (EPI == 1) {
                unsigned short* Cb = (unsigned short*)Cout;
#pragma unroll
                for (int r = 0; r < 4; ++r)
                    Cb[(size_t)(row0 + r) * ldc + col] = f2bf(acc[i][j][r]);
            } else if (EPI == 2) {
                float* Cf = (float*)Cout;
                const float bv = bias[col];
#pragma unroll
                for (int r = 0; r < 4; ++r) {
                    float v = acc[i][j][r] + bv;
                    Cf[(size_t)(row0 + r) * ldc + col] = (v > 20.f) ? v : log1pf(__expf(v));
                }
            } else {
                float* Cf = (float*)Cout;
#pragma unroll
                for (int r = 0; r < 4; ++r)
                    Cf[(size_t)(row0 + r) * ldc + col] = acc[i][j][r];
            }
        }
    }
}

// ---------------------------------------------------------------------------
// Split-K MFMA GEMM for x_proj (N=96): blockIdx.z = k-slice, partial C out.
// ---------------------------------------------------------------------------
__launch_bounds__(256)
__global__ void gemm_mfma_sk(const unsigned short* __restrict__ A,
                             const unsigned short* __restrict__ W,
                             float* __restrict__ Cpart,
                             int M, int N, int K, int lda, int ldb, int ldc, int kslices)
{
    __shared__ unsigned short Asub[128 * 32];
    __shared__ unsigned short Bsub[128 * 32];

    const int tid = threadIdx.x;
    const int l = tid & 63;
    const int w = tid >> 6;
    const int wr = w >> 1, wc = w & 1;
    const int brow = blockIdx.y * 128;
    const int bcol = blockIdx.x * 128;
    const int ks = blockIdx.z;
    const int klen = K / kslices;
    const int kbeg = ks * klen;
    float* C = Cpart + (size_t)ks * M * ldc;

    f32x4 acc[4][4];
#pragma unroll
    for (int i = 0; i < 4; ++i)
#pragma unroll
        for (int j = 0; j < 4; ++j) acc[i][j] = (f32x4)0.f;

    const int srow = tid >> 2;
    const int scol = (tid & 3) * 8;

    for (int k0 = kbeg; k0 < kbeg + klen; k0 += 32) {
#pragma unroll
        for (int i = 0; i < 2; ++i) {
            const int ar = brow + i * 64 + srow;
            const unsigned short* ga = A + (size_t)ar * lda + k0 + scol;
            __builtin_amdgcn_global_load_lds(GLB_PTR(ga),
                LDS_PTR((char*)Asub + i * 4096 + w * 1024), 16, 0, 0);
            int nr = bcol + i * 64 + srow;
            if (nr > N - 1) nr = N - 1;
            const unsigned short* gb = W + (size_t)nr * ldb + k0 + scol;
            __builtin_amdgcn_global_load_lds(GLB_PTR(gb),
                LDS_PTR((char*)Bsub + i * 4096 + w * 1024), 16, 0, 0);
        }
        __syncthreads();

        short8 af[4], bf[4];
#pragma unroll
        for (int i = 0; i < 4; ++i) {
            const int row = wr * 64 + i * 16 + (l & 15);
            af[i] = *(const short8*)((const char*)Asub + row * 64 + (l >> 4) * 16);
        }
#pragma unroll
        for (int j = 0; j < 4; ++j) {
            const int row = wc * 64 + j * 16 + (l & 15);
            bf[j] = *(const short8*)((const char*)Bsub + row * 64 + (l >> 4) * 16);
        }
#pragma unroll
        for (int i = 0; i < 4; ++i)
#pragma unroll
            for (int j = 0; j < 4; ++j)
                acc[i][j] = __builtin_amdgcn_mfma_f32_16x16x32_bf16(af[i], bf[j], acc[i][j], 0, 0, 0);
        __syncthreads();
    }

#pragma unroll
    for (int i = 0; i < 4; ++i) {
        const int row0 = brow + wr * 64 + i * 16 + ((l >> 4) * 4);
#pragma unroll
        for (int j = 0; j < 4; ++j) {
            const int col = bcol + wc * 64 + j * 16 + (l & 15);
            if (col < N) {
#pragma unroll
                for (int r = 0; r < 4; ++r)
                    C[(size_t)(row0 + r) * ldc + col] = acc[i][j][r];
            }
        }
    }
}

// sum partial slices -> xdbl (fp32) + compact bf16 copy of dt cols [0,64)
__launch_bounds__(256)
__global__ void sk_reduce(const float* __restrict__ part, float* __restrict__ out,
                          unsigned short* __restrict__ dtb, int n4, int slices)
{
    int i = blockIdx.x * 256 + threadIdx.x;
    if (i < n4) {
        float4 s = ((const float4*)part)[i];
        for (int k = 1; k < slices; ++k) {
            float4 p = ((const float4*)part)[(size_t)k * n4 + i];
            s.x += p.x; s.y += p.y; s.z += p.z; s.w += p.w;
        }
        ((float4*)out)[i] = s;
        const int r = i / 24, cq = i % 24;
        if (cq < 16) {
            uint2 o;
            o.x = (unsigned)f2bf(s.x) | ((unsigned)f2bf(s.y) << 16);
            o.y = (unsigned)f2bf(s.z) | ((unsigned)f2bf(s.w) << 16);
            *(uint2*)&dtb[(size_t)r * DTR + cq * 4] = o;
        }
    }
}

// ---------------------------------------------------------------------------
// Causal depthwise conv1d (width 4) + bias + silu.  bf16 in/out.
// ---------------------------------------------------------------------------
__launch_bounds__(256)
__global__ void conv_silu_kernel(const unsigned short* __restrict__ xzb,
                                 const float* __restrict__ cw,
                                 const float* __restrict__ cb,
                                 unsigned short* __restrict__ ub)
{
    const int orig = blockIdx.x;
    const int bl = (orig & 7) * (BLTOK / 8) + (orig >> 3);   // bijective (4096%8==0)
    const int l  = bl & (LSEQ - 1);
    const int d0 = threadIdx.x * 8;

    float acc[8];
    float4 w4[8];
#pragma unroll
    for (int q = 0; q < 8; ++q) {
        w4[q]  = *(const float4*)&cw[(d0 + q) * 4];
        acc[q] = cb[d0 + q];
    }
#pragma unroll
    for (int k = 0; k < 4; ++k) {
        const int ls = l - 3 + k;
        if (ls < 0) continue;
        short8 v = *(const short8*)&xzb[(size_t)(bl - 3 + k) * (2 * DI) + d0];
#pragma unroll
        for (int q = 0; q < 8; ++q) {
            const float wk = ((const float*)&w4[q])[k];
            acc[q] = fmaf(wk, bf2f((unsigned short)v[q]), acc[q]);
        }
    }
    short8 o;
#pragma unroll
    for (int q = 0; q < 8; ++q) {
        const float s = acc[q] / (1.f + __expf(-acc[q]));
        o[q] = (short)f2bf(s);
    }
    *(short8*)&ub[(size_t)bl * DI + d0] = o;
}

// ---------------------------------------------------------------------------
// Scan phase 1: per chunk, per (b,d): 16 n-states in registers.
// Direct coalesced loads; S4D fast path (dA[n] = w^(n+1)); P via dsum.
// ---------------------------------------------------------------------------
__launch_bounds__(256)
__global__ void scan_phase1(const float* __restrict__ delta, const unsigned short* __restrict__ ub,
                            const float* __restrict__ xdbl, const float* __restrict__ A_log,
                            float* __restrict__ P, float* __restrict__ S)
{
    __shared__ float sB[LC][NST];
    const int tid = threadIdx.x;
    const int d = blockIdx.x * 256 + tid;
    const int c = blockIdx.y;
    const int b = blockIdx.z;
    const int t0 = c * LC;

    for (int i = tid; i < LC * NST; i += 256)
        sB[i >> 4][i & 15] = xdbl[(size_t)(b * LSEQ + t0 + (i >> 4)) * 96 + 64 + (i & 15)];
    __syncthreads();

    // S4D structure check: Av[n] == (n+1)*Av0 ?
    const float Av0 = -__expf(A_log[d * NST]) * LOG2E;
    bool fast = true;
    for (int n = 1; n < NST; ++n) {
        const float avn = -__expf(A_log[d * NST + n]) * LOG2E;
        fast &= (fabsf(avn - (float)(n + 1) * Av0) <= 1e-3f * fabsf(avn));
    }

    float Sv[NST];
    float dsum = 0.f;
#pragma unroll
    for (int n = 0; n < NST; ++n) Sv[n] = 0.f;

    const float*          dbase = delta + (size_t)(b * LSEQ + t0) * DI + d;
    const unsigned short* ubase = ub    + (size_t)(b * LSEQ + t0) * DI + d;

    if (fast) {
        for (int tg = 0; tg < LC; tg += 4) {
            float dl[4], uu[4];
#pragma unroll
            for (int q = 0; q < 4; ++q) {
                dl[q] = dbase[(size_t)(tg + q) * DI];
                uu[q] = bf2f(ubase[(size_t)(tg + q) * DI]);
            }
#pragma unroll
            for (int q = 0; q < 4; ++q) {
                const float du = dl[q] * uu[q];
                dsum += dl[q];
                float e[NST];
                pow_tree(__builtin_amdgcn_exp2f(dl[q] * Av0), e);
#pragma unroll
                for (int n = 0; n < NST; ++n)
                    Sv[n] = fmaf(e[n], Sv[n], du * sB[tg + q][n]);
            }
        }
        float Pv[NST];
        pow_tree(__builtin_amdgcn_exp2f(dsum * Av0), Pv);
        const size_t base = ((size_t)(b * CH + c) * DI + d) * NST;
#pragma unroll
        for (int n = 0; n < NST; n += 4) {
            *(f32x4*)&P[base + n] = (f32x4){Pv[n], Pv[n+1], Pv[n+2], Pv[n+3]};
            *(f32x4*)&S[base + n] = (f32x4){Sv[n], Sv[n+1], Sv[n+2], Sv[n+3]};
        }
    } else {
        // generic fallback (never taken for the S4D init; correct regardless)
        for (int t = 0; t < LC; ++t) {
            const float dlt = dbase[(size_t)t * DI];
            const float uu  = bf2f(ubase[(size_t)t * DI]);
            const float du  = dlt * uu;
            dsum += dlt;
            for (int n = 0; n < NST; ++n) {
                const float avn = -__expf(A_log[d * NST + n]) * LOG2E;
                const float dA = __builtin_amdgcn_exp2f(dlt * avn);
                Sv[n] = fmaf(dA, Sv[n], du * sB[t][n]);
            }
        }
        const size_t base = ((size_t)(b * CH + c) * DI + d) * NST;
        for (int n = 0; n < NST; ++n) {
            const float avn = -__expf(A_log[d * NST + n]) * LOG2E;
            P[base + n] = __builtin_amdgcn_exp2f(dsum * avn);
            S[base + n] = Sv[n];
        }
    }
}

// ---------------------------------------------------------------------------
// Scan phase 2: sequential combine over chunks.
// ---------------------------------------------------------------------------
__launch_bounds__(256)
__global__ void scan_phase2(const float* __restrict__ P, const float* __restrict__ S,
                            float* __restrict__ hin)
{
    const int g = blockIdx.x * 256 + threadIdx.x;
    const int n = g & 15;
    const int d = (g >> 4) & (DI - 1);
    const int b = g >> 15;
    float h = 0.f;
#pragma unroll 4
    for (int c = 0; c < CH; ++c) {
        const size_t idx = ((size_t)(b * CH + c) * DI + d) * NST + n;
        hin[idx] = h;
        h = fmaf(P[idx], h, S[idx]);
    }
}

// ---------------------------------------------------------------------------
// Scan phase 3: replay chunk with h_in; fuse D-skip + silu(z) gating; bf16 out.
// Direct coalesced loads; S4D fast path.
// ---------------------------------------------------------------------------
__launch_bounds__(256)
__global__ void scan_phase3(const float* __restrict__ delta, const unsigned short* __restrict__ ub,
                            const float* __restrict__ xdbl, const float* __restrict__ A_log,
                            const float* __restrict__ Dskip, const unsigned short* __restrict__ xzb,
                            const float* __restrict__ hin, unsigned short* __restrict__ yg)
{
    __shared__ float sB[LC][NST], sC[LC][NST];
    const int tid = threadIdx.x;
    const int d = blockIdx.x * 256 + tid;
    const int c = blockIdx.y;
    const int b = blockIdx.z;
    const int t0 = c * LC;

    for (int i = tid; i < LC * NST; i += 256) {
        const size_t row = (size_t)(b * LSEQ + t0 + (i >> 4)) * 96;
        sB[i >> 4][i & 15] = xdbl[row + 64 + (i & 15)];
        sC[i >> 4][i & 15] = xdbl[row + 80 + (i & 15)];
    }
    __syncthreads();

    const float Av0 = -__expf(A_log[d * NST]) * LOG2E;
    bool fast = true;
    for (int n = 1; n < NST; ++n) {
        const float avn = -__expf(A_log[d * NST + n]) * LOG2E;
        fast &= (fabsf(avn - (float)(n + 1) * Av0) <= 1e-3f * fabsf(avn));
    }

    float h[NST];
    const size_t hbase = ((size_t)(b * CH + c) * DI + d) * NST;
#pragma unroll
    for (int n = 0; n < NST; n += 4) {
        f32x4 t = *(const f32x4*)&hin[hbase + n];
        h[n] = t.x; h[n+1] = t.y; h[n+2] = t.z; h[n+3] = t.w;
    }
    const float Dskv = Dskip[d];

    const float*          dbase = delta + (size_t)(b * LSEQ + t0) * DI + d;
    const unsigned short* ubase = ub    + (size_t)(b * LSEQ + t0) * DI + d;
    const unsigned short* zbase = xzb   + (size_t)(b * LSEQ + t0) * (2 * DI) + DI + d;
    unsigned short* yrow = yg + (size_t)(b * LSEQ + t0) * DI + d;

    if (fast) {
        for (int tg = 0; tg < LC; tg += 4) {
            float dl[4], uu[4], zz[4];
#pragma unroll
            for (int q = 0; q < 4; ++q) {
                dl[q] = dbase[(size_t)(tg + q) * DI];
                uu[q] = bf2f(ubase[(size_t)(tg + q) * DI]);
                zz[q] = bf2f(zbase[(size_t)(tg + q) * (2 * DI)]);
            }
#pragma unroll
            for (int q = 0; q < 4; ++q) {
                const float du = dl[q] * uu[q];
                float e[NST];
                pow_tree(__builtin_amdgcn_exp2f(dl[q] * Av0), e);
                float y = 0.f;
#pragma unroll
                for (int n = 0; n < NST; ++n) {
                    h[n] = fmaf(e[n], h[n], du * sB[tg + q][n]);
                    y = fmaf(h[n], sC[tg + q][n], y);
                }
                const float zv = zz[q];
                const float sig = __frcp_rn(1.f + __expf(-zv));
                const float val = (y + uu[q] * Dskv) * (zv * sig);
                yrow[(size_t)(tg + q) * DI] = f2bf(val);
            }
        }
    } else {
        for (int t = 0; t < LC; ++t) {
            const float dlt = dbase[(size_t)t * DI];
            const float uu  = bf2f(ubase[(size_t)t * DI]);
            const float zv  = bf2f(zbase[(size_t)t * (2 * DI)]);
            const float du  = dlt * uu;
            float y = 0.f;
            for (int n = 0; n < NST; ++n) {
                const float avn = -__expf(A_log[d * NST + n]) * LOG2E;
                const float dA = __builtin_amdgcn_exp2f(dlt * avn);
                h[n] = fmaf(dA, h[n], du * sB[t][n]);
                y = fmaf(h[n], sC[t][n], y);
            }
            const float sig = __frcp_rn(1.f + __expf(-zv));
            const float val = (y + uu * Dskv) * (zv * sig);
            yrow[(size_t)t * DI] = f2bf(val);
        }
    }
}

// ---------------------------------------------------------------------------
extern "C" void kernel_launch(void* const* d_in, const int* in_sizes, int n_in,
                              void* d_out, int out_size, void* d_ws, size_t ws_size,
                              hipStream_t stream)
{
    const float* x        = (const float*)d_in[0];
    const float* in_w     = (const float*)d_in[1];
    const float* conv_w   = (const float*)d_in[2];
    const float* conv_b   = (const float*)d_in[3];
    const float* xproj_w  = (const float*)d_in[4];
    const float* dtproj_w = (const float*)d_in[5];
    const float* dtproj_b = (const float*)d_in[6];
    const float* A_log    = (const float*)d_in[7];
    const float* Dskip    = (const float*)d_in[8];
    const float* out_w    = (const float*)d_in[9];
    float* out = (float*)d_out;

    char* ws = (char*)d_ws;
#define MB(x) ((size_t)(x) * 1024 * 1024)
    unsigned short* xzb   = (unsigned short*)(ws);           // bf16 [4096,4096] 32 MB
    unsigned short* ub    = (unsigned short*)(ws + MB(32));  // bf16 [4096,2048] 16 MB
    float*          delta = (float*)(ws + MB(48));           // fp32 [4096,2048] 32 MB
    float*          xdbl  = (float*)(ws + MB(80));           // fp32 [4096,96]  1.5 MB
    unsigned short* ygb   = (unsigned short*)(ws + MB(82));  // bf16 [4096,2048] 16 MB
    float*          P     = (float*)(ws + MB(98));           // 32 MB (CH=128; also x_proj partials)
    float*          S     = (float*)(ws + MB(130));          // 32 MB
    float*          hin   = (float*)(ws + MB(162));          // 32 MB
    unsigned short* xb    = (unsigned short*)(ws + MB(194)); // bf16 x      8 MB
    unsigned short* wb1   = (unsigned short*)(ws + MB(202)); // bf16 in_w   8 MB
    unsigned short* wb3   = (unsigned short*)(ws + MB(210)); // bf16 xproj  0.4 MB
    unsigned short* wb6   = (unsigned short*)(ws + MB(211)); // bf16 out_w  4 MB
    unsigned short* wb5   = (unsigned short*)(ws + MB(215)); // bf16 dtproj_w 0.25 MB
    unsigned short* dtb   = (unsigned short*)(ws + MB(216)); // bf16 dt [4096,64] 0.5 MB
    float*          xdbl_part = P;                           // 8 x [4096,96]

    dim3 blk(256);

    cast_bf16<<<dim3((BLTOK * DM / 4 + 255) / 256), blk, 0, stream>>>(x, xb, BLTOK * DM / 4);
    cast_bf16<<<dim3((2 * DI * DM / 4 + 255) / 256), blk, 0, stream>>>(in_w, wb1, 2 * DI * DM / 4);
    cast_bf16<<<dim3((96 * DI / 4 + 255) / 256), blk, 0, stream>>>(xproj_w, wb3, 96 * DI / 4);
    cast_bf16<<<dim3((DM * DI / 4 + 255) / 256), blk, 0, stream>>>(out_w, wb6, DM * DI / 4);
    cast_bf16<<<dim3((DI * DTR / 4 + 255) / 256), blk, 0, stream>>>(dtproj_w, wb5, DI * DTR / 4);

    // 1) in_proj: xzb = bf16(x @ in_w^T)   [4096 x 4096], K=1024
    gemm_db<1><<<dim3(32, 32), blk, 0, stream>>>(xb, wb1, xzb, nullptr,
                                                 BLTOK, 2 * DI, DM, DM, DM, 2 * DI);

    // 2) conv + silu -> ub (bf16)
    conv_silu_kernel<<<dim3(BLTOK), blk, 0, stream>>>(xzb, conv_w, conv_b, ub);

    // 3) x_proj split-K=8: partials then reduce (fp32 xdbl + bf16 dt copy)
    gemm_mfma_sk<<<dim3(1, 32, 8), blk, 0, stream>>>(ub, wb3, xdbl_part,
                                                     BLTOK, DTR + 2 * NST, DI, DI, DI, 96, 8);
    sk_reduce<<<dim3((BLTOK * 96 / 4 + 255) / 256), blk, 0, stream>>>(xdbl_part, xdbl, dtb,
                                                                      BLTOK * 96 / 4, 8);

    // 4) dt_proj + softplus: delta = softplus(dtb @ wb5^T + b)  [4096 x 2048], K=64 (MFMA)
    gemm_db<2><<<dim3(16, 32), blk, 0, stream>>>(dtb, wb5, delta, dtproj_b,
                                                 BLTOK, DI, DTR, DTR, DTR, DI);

    // 5) chunked selective scan (CH=128, LC=16)
    scan_phase1<<<dim3(DI / 256, CH, NB), blk, 0, stream>>>(delta, ub, xdbl, A_log, P, S);
    scan_phase2<<<dim3(NB * DI * NST / 256), blk, 0, stream>>>(P, S, hin);
    scan_phase3<<<dim3(DI / 256, CH, NB), blk, 0, stream>>>(delta, ub, xdbl, A_log, Dskip,
                                                            xzb, hin, ygb);

    // 6) out_proj: out = yg @ out_w^T   [4096 x 1024], K=2048
    gemm_db<0><<<dim3(8, 32), blk, 0, stream>>>(ygb, wb6, out, nullptr,
                                                BLTOK, DM, DI, DI, DI, DM);
}

// Round 7
// 219.554 us; speedup vs baseline: 7.6422x; 1.1598x over previous
//
#include <hip/hip_runtime.h>
#include <hip/hip_bf16.h>
#include <math.h>

// Problem constants (MambaBlock: D_MODEL=1024, D_STATE=16, D_CONV=4, EXPAND=2, DT_RANK=64)
#define NB      2
#define LSEQ    2048
#define BLTOK   4096      // NB * LSEQ
#define DM      1024
#define DI      2048      // EXPAND * DM
#define NST     16
#define DTR     64
#define CH      64        // scan chunks
#define LC      32        // LSEQ / CH
#define LOG2E   1.44269504f

typedef __attribute__((ext_vector_type(8))) short short8;
typedef __attribute__((ext_vector_type(4))) float f32x4;

#define LDS_PTR(p) ((__attribute__((address_space(3))) void*)(p))
#define GLB_PTR(p) ((const __attribute__((address_space(1))) void*)(p))

static __device__ __forceinline__ unsigned short f2bf(float f) {
    unsigned int u = __float_as_uint(f);
    unsigned int r = (u + 0x7FFFu + ((u >> 16) & 1u)) >> 16;   // RNE
    return (unsigned short)r;
}
static __device__ __forceinline__ float bf2f(unsigned short v) {
    return __uint_as_float((unsigned int)v << 16);
}

// w^(n+1) for n=0..15 via binary tree (depth 4, 15 full-rate muls)
static __device__ __forceinline__ void pow_tree(float w, float* e) {
    e[0]  = w;
    e[1]  = e[0] * e[0];
    e[2]  = e[1] * e[0];
    e[3]  = e[1] * e[1];
    e[4]  = e[3] * e[0];
    e[5]  = e[3] * e[1];
    e[6]  = e[3] * e[2];
    e[7]  = e[3] * e[3];
    e[8]  = e[7] * e[0];
    e[9]  = e[7] * e[1];
    e[10] = e[7] * e[2];
    e[11] = e[7] * e[3];
    e[12] = e[7] * e[4];
    e[13] = e[7] * e[5];
    e[14] = e[7] * e[6];
    e[15] = e[7] * e[7];
}

// ---------------------------------------------------------------------------
// Fused fp32 -> bf16 cast of all 5 weight/activation tensors (one launch).
// Sizes in float4 units; if-chain by range.
// ---------------------------------------------------------------------------
#define C4_X   (BLTOK * DM / 4)           // 1048576
#define C4_W1  (2 * DI * DM / 4)          // 1048576
#define C4_W3  (96 * DI / 4)              // 49152
#define C4_W6  (DM * DI / 4)              // 524288
#define C4_W5  (DI * DTR / 4)             // 32768
#define C4_TOT (C4_X + C4_W1 + C4_W3 + C4_W6 + C4_W5)

__launch_bounds__(256)
__global__ void cast_all(const float* __restrict__ x,   unsigned short* __restrict__ xb,
                         const float* __restrict__ w1,  unsigned short* __restrict__ wb1,
                         const float* __restrict__ w3,  unsigned short* __restrict__ wb3,
                         const float* __restrict__ w6,  unsigned short* __restrict__ wb6,
                         const float* __restrict__ w5,  unsigned short* __restrict__ wb5)
{
    int i = blockIdx.x * 256 + threadIdx.x;
    if (i >= C4_TOT) return;
    const float* in; unsigned short* out;
    if (i < C4_X)                         { in = x;  out = xb;  }
    else if ((i -= C4_X) < C4_W1)         { in = w1; out = wb1; }
    else if ((i -= C4_W1) < C4_W3)        { in = w3; out = wb3; }
    else if ((i -= C4_W3) < C4_W6)        { in = w6; out = wb6; }
    else       { i -= C4_W6;                in = w5; out = wb5; }
    float4 v = ((const float4*)in)[i];
    uint2 o;
    o.x = (unsigned)f2bf(v.x) | ((unsigned)f2bf(v.y) << 16);
    o.y = (unsigned)f2bf(v.z) | ((unsigned)f2bf(v.w) << 16);
    ((uint2*)out)[i] = o;
}

// ---------------------------------------------------------------------------
// bf16 MFMA GEMM, BK=64 double-buffered 2-phase pipeline.
// LDS XOR swizzle (both-sides). M,N mult of 128, K mult of 64.
// EPI 0: fp32 C.  EPI 1: bf16 C.  EPI 2: fp32 softplus(acc+bias[col]).
// EPI 3: bf16 softplus(acc+bias[col]).
// ---------------------------------------------------------------------------
template<int EPI>
__launch_bounds__(256)
__global__ void gemm_db(const unsigned short* __restrict__ A,
                        const unsigned short* __restrict__ W,
                        void* __restrict__ Cout,
                        const float* __restrict__ bias,
                        int M, int N, int K, int lda, int ldb, int ldc)
{
    __shared__ unsigned short lds[2][2][128 * 64];   // 64 KB

    const int tid = threadIdx.x;
    const int l = tid & 63;
    const int w = tid >> 6;
    const int wr = w >> 1, wc = w & 1;
    const int brow = blockIdx.y * 128;
    const int bcol = blockIdx.x * 128;

    const int strow = tid >> 3;                          // 0..31
    const int scol  = ((tid & 7) ^ (strow & 7)) * 8;     // swizzled source col

    f32x4 acc[4][4];
#pragma unroll
    for (int i = 0; i < 4; ++i)
#pragma unroll
        for (int j = 0; j < 4; ++j) acc[i][j] = (f32x4)0.f;

    auto stage = [&](int bb, int k0) {
#pragma unroll
        for (int i = 0; i < 4; ++i) {
            const unsigned short* ga = A + (size_t)(brow + i * 32 + strow) * lda + k0 + scol;
            __builtin_amdgcn_global_load_lds(GLB_PTR(ga),
                LDS_PTR((char*)&lds[bb][0][0] + (i * 32 + w * 8) * 128), 16, 0, 0);
            const unsigned short* gb = W + (size_t)(bcol + i * 32 + strow) * ldb + k0 + scol;
            __builtin_amdgcn_global_load_lds(GLB_PTR(gb),
                LDS_PTR((char*)&lds[bb][1][0] + (i * 32 + w * 8) * 128), 16, 0, 0);
        }
    };

    auto compute = [&](int bb) {
        const char* baseA = (const char*)&lds[bb][0][0];
        const char* baseB = (const char*)&lds[bb][1][0];
        const int xo  = (l & 7) * 16;
        const int ko0 = (l >> 4) * 16;
#pragma unroll
        for (int ks = 0; ks < 2; ++ks) {
            const int kb = ks * 64 + ko0;
            short8 af[4], bfr[4];
#pragma unroll
            for (int i = 0; i < 4; ++i) {
                const int rowA = wr * 64 + i * 16 + (l & 15);
                af[i] = *(const short8*)(baseA + rowA * 128 + (kb ^ xo));
                const int rowB = wc * 64 + i * 16 + (l & 15);
                bfr[i] = *(const short8*)(baseB + rowB * 128 + (kb ^ xo));
            }
#pragma unroll
            for (int i = 0; i < 4; ++i)
#pragma unroll
                for (int j = 0; j < 4; ++j)
                    acc[i][j] = __builtin_amdgcn_mfma_f32_16x16x32_bf16(af[i], bfr[j], acc[i][j], 0, 0, 0);
        }
    };

    const int nt = K / 64;
    stage(0, 0);
    __syncthreads();
    int cur = 0;
    for (int t = 0; t < nt - 1; ++t) {
        stage(cur ^ 1, (t + 1) * 64);
        compute(cur);
        __syncthreads();
        cur ^= 1;
    }
    compute(cur);

#pragma unroll
    for (int i = 0; i < 4; ++i) {
        const int row0 = brow + wr * 64 + i * 16 + ((l >> 4) * 4);
#pragma unroll
        for (int j = 0; j < 4; ++j) {
            const int col = bcol + wc * 64 + j * 16 + (l & 15);
            if (EPI == 1) {
                unsigned short* Cb = (unsigned short*)Cout;
#pragma unroll
                for (int r = 0; r < 4; ++r)
                    Cb[(size_t)(row0 + r) * ldc + col] = f2bf(acc[i][j][r]);
            } else if (EPI == 2 || EPI == 3) {
                const float bv = bias[col];
#pragma unroll
                for (int r = 0; r < 4; ++r) {
                    float v = acc[i][j][r] + bv;
                    v = (v > 20.f) ? v : log1pf(__expf(v));
                    if (EPI == 2) ((float*)Cout)[(size_t)(row0 + r) * ldc + col] = v;
                    else ((unsigned short*)Cout)[(size_t)(row0 + r) * ldc + col] = f2bf(v);
                }
            } else {
                float* Cf = (float*)Cout;
#pragma unroll
                for (int r = 0; r < 4; ++r)
                    Cf[(size_t)(row0 + r) * ldc + col] = acc[i][j][r];
            }
        }
    }
}

// ---------------------------------------------------------------------------
// Split-K MFMA GEMM for x_proj (N=96): blockIdx.z = k-slice, partial C out.
// ---------------------------------------------------------------------------
__launch_bounds__(256)
__global__ void gemm_mfma_sk(const unsigned short* __restrict__ A,
                             const unsigned short* __restrict__ W,
                             float* __restrict__ Cpart,
                             int M, int N, int K, int lda, int ldb, int ldc, int kslices)
{
    __shared__ unsigned short Asub[128 * 32];
    __shared__ unsigned short Bsub[128 * 32];

    const int tid = threadIdx.x;
    const int l = tid & 63;
    const int w = tid >> 6;
    const int wr = w >> 1, wc = w & 1;
    const int brow = blockIdx.y * 128;
    const int bcol = blockIdx.x * 128;
    const int ks = blockIdx.z;
    const int klen = K / kslices;
    const int kbeg = ks * klen;
    float* C = Cpart + (size_t)ks * M * ldc;

    f32x4 acc[4][4];
#pragma unroll
    for (int i = 0; i < 4; ++i)
#pragma unroll
        for (int j = 0; j < 4; ++j) acc[i][j] = (f32x4)0.f;

    const int srow = tid >> 2;
    const int scol = (tid & 3) * 8;

    for (int k0 = kbeg; k0 < kbeg + klen; k0 += 32) {
#pragma unroll
        for (int i = 0; i < 2; ++i) {
            const int ar = brow + i * 64 + srow;
            const unsigned short* ga = A + (size_t)ar * lda + k0 + scol;
            __builtin_amdgcn_global_load_lds(GLB_PTR(ga),
                LDS_PTR((char*)Asub + i * 4096 + w * 1024), 16, 0, 0);
            int nr = bcol + i * 64 + srow;
            if (nr > N - 1) nr = N - 1;
            const unsigned short* gb = W + (size_t)nr * ldb + k0 + scol;
            __builtin_amdgcn_global_load_lds(GLB_PTR(gb),
                LDS_PTR((char*)Bsub + i * 4096 + w * 1024), 16, 0, 0);
        }
        __syncthreads();

        short8 af[4], bf[4];
#pragma unroll
        for (int i = 0; i < 4; ++i) {
            const int row = wr * 64 + i * 16 + (l & 15);
            af[i] = *(const short8*)((const char*)Asub + row * 64 + (l >> 4) * 16);
        }
#pragma unroll
        for (int j = 0; j < 4; ++j) {
            const int row = wc * 64 + j * 16 + (l & 15);
            bf[j] = *(const short8*)((const char*)Bsub + row * 64 + (l >> 4) * 16);
        }
#pragma unroll
        for (int i = 0; i < 4; ++i)
#pragma unroll
            for (int j = 0; j < 4; ++j)
                acc[i][j] = __builtin_amdgcn_mfma_f32_16x16x32_bf16(af[i], bf[j], acc[i][j], 0, 0, 0);
        __syncthreads();
    }

#pragma unroll
    for (int i = 0; i < 4; ++i) {
        const int row0 = brow + wr * 64 + i * 16 + ((l >> 4) * 4);
#pragma unroll
        for (int j = 0; j < 4; ++j) {
            const int col = bcol + wc * 64 + j * 16 + (l & 15);
            if (col < N) {
#pragma unroll
                for (int r = 0; r < 4; ++r)
                    C[(size_t)(row0 + r) * ldc + col] = acc[i][j][r];
            }
        }
    }
}

// sum partial slices -> xdbl (fp32) + compact bf16 copy of dt cols [0,64)
__launch_bounds__(256)
__global__ void sk_reduce(const float* __restrict__ part, float* __restrict__ out,
                          unsigned short* __restrict__ dtb, int n4, int slices)
{
    int i = blockIdx.x * 256 + threadIdx.x;
    if (i < n4) {
        float4 s = ((const float4*)part)[i];
        for (int k = 1; k < slices; ++k) {
            float4 p = ((const float4*)part)[(size_t)k * n4 + i];
            s.x += p.x; s.y += p.y; s.z += p.z; s.w += p.w;
        }
        ((float4*)out)[i] = s;
        const int r = i / 24, cq = i % 24;
        if (cq < 16) {
            uint2 o;
            o.x = (unsigned)f2bf(s.x) | ((unsigned)f2bf(s.y) << 16);
            o.y = (unsigned)f2bf(s.z) | ((unsigned)f2bf(s.w) << 16);
            *(uint2*)&dtb[(size_t)r * DTR + cq * 4] = o;
        }
    }
}

// ---------------------------------------------------------------------------
// Causal depthwise conv1d (width 4) + bias + silu.  bf16 in/out.
// ---------------------------------------------------------------------------
__launch_bounds__(256)
__global__ void conv_silu_kernel(const unsigned short* __restrict__ xzb,
                                 const float* __restrict__ cw,
                                 const float* __restrict__ cb,
                                 unsigned short* __restrict__ ub)
{
    const int orig = blockIdx.x;
    const int bl = (orig & 7) * (BLTOK / 8) + (orig >> 3);   // bijective (4096%8==0)
    const int l  = bl & (LSEQ - 1);
    const int d0 = threadIdx.x * 8;

    float acc[8];
    float4 w4[8];
#pragma unroll
    for (int q = 0; q < 8; ++q) {
        w4[q]  = *(const float4*)&cw[(d0 + q) * 4];
        acc[q] = cb[d0 + q];
    }
#pragma unroll
    for (int k = 0; k < 4; ++k) {
        const int ls = l - 3 + k;
        if (ls < 0) continue;
        short8 v = *(const short8*)&xzb[(size_t)(bl - 3 + k) * (2 * DI) + d0];
#pragma unroll
        for (int q = 0; q < 8; ++q) {
            const float wk = ((const float*)&w4[q])[k];
            acc[q] = fmaf(wk, bf2f((unsigned short)v[q]), acc[q]);
        }
    }
    short8 o;
#pragma unroll
    for (int q = 0; q < 8; ++q) {
        const float s = acc[q] / (1.f + __expf(-acc[q]));
        o[q] = (short)f2bf(s);
    }
    *(short8*)&ub[(size_t)bl * DI + d0] = o;
}

// ---------------------------------------------------------------------------
// Scan phase 1: per chunk, per (b,d): 16 n-states in registers.
// delta bf16; S4D fast path (dA[n] = w^(n+1)); stores S + dsum (no P).
// ---------------------------------------------------------------------------
__launch_bounds__(256)
__global__ void scan_phase1(const unsigned short* __restrict__ delta,
                            const unsigned short* __restrict__ ub,
                            const float* __restrict__ xdbl, const float* __restrict__ A_log,
                            float* __restrict__ S, float* __restrict__ dsum_out)
{
    __shared__ float sB[LC][NST];
    const int tid = threadIdx.x;
    const int d = blockIdx.x * 256 + tid;
    const int c = blockIdx.y;
    const int b = blockIdx.z;
    const int t0 = c * LC;

    for (int i = tid; i < LC * NST; i += 256)
        sB[i >> 4][i & 15] = xdbl[(size_t)(b * LSEQ + t0 + (i >> 4)) * 96 + 64 + (i & 15)];
    __syncthreads();

    // S4D structure check: Av[n] == (n+1)*Av0 ?
    const float Av0 = -__expf(A_log[d * NST]) * LOG2E;
    bool fast = true;
    for (int n = 1; n < NST; ++n) {
        const float avn = -__expf(A_log[d * NST + n]) * LOG2E;
        fast &= (fabsf(avn - (float)(n + 1) * Av0) <= 1e-3f * fabsf(avn));
    }

    float Sv[NST];
    float dsum = 0.f;
#pragma unroll
    for (int n = 0; n < NST; ++n) Sv[n] = 0.f;

    const unsigned short* dbase = delta + (size_t)(b * LSEQ + t0) * DI + d;
    const unsigned short* ubase = ub    + (size_t)(b * LSEQ + t0) * DI + d;

    if (fast) {
        for (int tg = 0; tg < LC; tg += 4) {
            float dl[4], uu[4];
#pragma unroll
            for (int q = 0; q < 4; ++q) {
                dl[q] = bf2f(dbase[(size_t)(tg + q) * DI]);
                uu[q] = bf2f(ubase[(size_t)(tg + q) * DI]);
            }
#pragma unroll
            for (int q = 0; q < 4; ++q) {
                const float du = dl[q] * uu[q];
                dsum += dl[q];
                float e[NST];
                pow_tree(__builtin_amdgcn_exp2f(dl[q] * Av0), e);
#pragma unroll
                for (int n = 0; n < NST; ++n)
                    Sv[n] = fmaf(e[n], Sv[n], du * sB[tg + q][n]);
            }
        }
    } else {
        for (int t = 0; t < LC; ++t) {
            const float dlt = bf2f(dbase[(size_t)t * DI]);
            const float uu  = bf2f(ubase[(size_t)t * DI]);
            const float du  = dlt * uu;
            dsum += dlt;
            for (int n = 0; n < NST; ++n) {
                const float avn = -__expf(A_log[d * NST + n]) * LOG2E;
                const float dA = __builtin_amdgcn_exp2f(dlt * avn);
                Sv[n] = fmaf(dA, Sv[n], du * sB[t][n]);
            }
        }
    }

    const size_t base = ((size_t)(b * CH + c) * DI + d) * NST;
#pragma unroll
    for (int n = 0; n < NST; n += 4)
        *(f32x4*)&S[base + n] = (f32x4){Sv[n], Sv[n+1], Sv[n+2], Sv[n+3]};
    dsum_out[(size_t)(b * CH + c) * DI + d] = dsum;
}

// ---------------------------------------------------------------------------
// Scan phase 2: sequential combine over chunks; recompute P from dsum.
// ---------------------------------------------------------------------------
__launch_bounds__(256)
__global__ void scan_phase2(const float* __restrict__ S, const float* __restrict__ dsum,
                            const float* __restrict__ A_log, float* __restrict__ hin)
{
    const int g = blockIdx.x * 256 + threadIdx.x;
    const int n = g & 15;
    const int d = (g >> 4) & (DI - 1);
    const int b = g >> 15;
    const float avn = -__expf(A_log[d * NST + n]) * LOG2E;
    float h = 0.f;
    for (int c = 0; c < CH; ++c) {
        const size_t idx = ((size_t)(b * CH + c) * DI + d) * NST + n;
        hin[idx] = h;
        const float Pc = __builtin_amdgcn_exp2f(dsum[(size_t)(b * CH + c) * DI + d] * avn);
        h = fmaf(Pc, h, S[idx]);
    }
}

// ---------------------------------------------------------------------------
// Scan phase 3: replay chunk with h_in; fuse D-skip + silu(z) gating; bf16 out.
// delta bf16.
// ---------------------------------------------------------------------------
__launch_bounds__(256)
__global__ void scan_phase3(const unsigned short* __restrict__ delta,
                            const unsigned short* __restrict__ ub,
                            const float* __restrict__ xdbl, const float* __restrict__ A_log,
                            const float* __restrict__ Dskip, const unsigned short* __restrict__ xzb,
                            const float* __restrict__ hin, unsigned short* __restrict__ yg)
{
    __shared__ float sB[LC][NST], sC[LC][NST];
    const int tid = threadIdx.x;
    const int d = blockIdx.x * 256 + tid;
    const int c = blockIdx.y;
    const int b = blockIdx.z;
    const int t0 = c * LC;

    for (int i = tid; i < LC * NST; i += 256) {
        const size_t row = (size_t)(b * LSEQ + t0 + (i >> 4)) * 96;
        sB[i >> 4][i & 15] = xdbl[row + 64 + (i & 15)];
        sC[i >> 4][i & 15] = xdbl[row + 80 + (i & 15)];
    }
    __syncthreads();

    const float Av0 = -__expf(A_log[d * NST]) * LOG2E;
    bool fast = true;
    for (int n = 1; n < NST; ++n) {
        const float avn = -__expf(A_log[d * NST + n]) * LOG2E;
        fast &= (fabsf(avn - (float)(n + 1) * Av0) <= 1e-3f * fabsf(avn));
    }

    float h[NST];
    const size_t hbase = ((size_t)(b * CH + c) * DI + d) * NST;
#pragma unroll
    for (int n = 0; n < NST; n += 4) {
        f32x4 t = *(const f32x4*)&hin[hbase + n];
        h[n] = t.x; h[n+1] = t.y; h[n+2] = t.z; h[n+3] = t.w;
    }
    const float Dskv = Dskip[d];

    const unsigned short* dbase = delta + (size_t)(b * LSEQ + t0) * DI + d;
    const unsigned short* ubase = ub    + (size_t)(b * LSEQ + t0) * DI + d;
    const unsigned short* zbase = xzb   + (size_t)(b * LSEQ + t0) * (2 * DI) + DI + d;
    unsigned short* yrow = yg + (size_t)(b * LSEQ + t0) * DI + d;

    if (fast) {
        for (int tg = 0; tg < LC; tg += 4) {
            float dl[4], uu[4], zz[4];
#pragma unroll
            for (int q = 0; q < 4; ++q) {
                dl[q] = bf2f(dbase[(size_t)(tg + q) * DI]);
                uu[q] = bf2f(ubase[(size_t)(tg + q) * DI]);
                zz[q] = bf2f(zbase[(size_t)(tg + q) * (2 * DI)]);
            }
#pragma unroll
            for (int q = 0; q < 4; ++q) {
                const float du = dl[q] * uu[q];
                float e[NST];
                pow_tree(__builtin_amdgcn_exp2f(dl[q] * Av0), e);
                float y = 0.f;
#pragma unroll
                for (int n = 0; n < NST; ++n) {
                    h[n] = fmaf(e[n], h[n], du * sB[tg + q][n]);
                    y = fmaf(h[n], sC[tg + q][n], y);
                }
                const float zv = zz[q];
                const float sig = __frcp_rn(1.f + __expf(-zv));
                const float val = (y + uu[q] * Dskv) * (zv * sig);
                yrow[(size_t)(tg + q) * DI] = f2bf(val);
            }
        }
    } else {
        for (int t = 0; t < LC; ++t) {
            const float dlt = bf2f(dbase[(size_t)t * DI]);
            const float uu  = bf2f(ubase[(size_t)t * DI]);
            const float zv  = bf2f(zbase[(size_t)t * (2 * DI)]);
            const float du  = dlt * uu;
            float y = 0.f;
            for (int n = 0; n < NST; ++n) {
                const float avn = -__expf(A_log[d * NST + n]) * LOG2E;
                const float dA = __builtin_amdgcn_exp2f(dlt * avn);
                h[n] = fmaf(dA, h[n], du * sB[t][n]);
                y = fmaf(h[n], sC[t][n], y);
            }
            const float sig = __frcp_rn(1.f + __expf(-zv));
            const float val = (y + uu * Dskv) * (zv * sig);
            yrow[(size_t)t * DI] = f2bf(val);
        }
    }
}

// ---------------------------------------------------------------------------
extern "C" void kernel_launch(void* const* d_in, const int* in_sizes, int n_in,
                              void* d_out, int out_size, void* d_ws, size_t ws_size,
                              hipStream_t stream)
{
    const float* x        = (const float*)d_in[0];
    const float* in_w     = (const float*)d_in[1];
    const float* conv_w   = (const float*)d_in[2];
    const float* conv_b   = (const float*)d_in[3];
    const float* xproj_w  = (const float*)d_in[4];
    const float* dtproj_w = (const float*)d_in[5];
    const float* dtproj_b = (const float*)d_in[6];
    const float* A_log    = (const float*)d_in[7];
    const float* Dskip    = (const float*)d_in[8];
    const float* out_w    = (const float*)d_in[9];
    float* out = (float*)d_out;

    char* ws = (char*)d_ws;
#define MB(x) ((size_t)(x) * 1024 * 1024)
    unsigned short* xzb   = (unsigned short*)(ws);           // bf16 [4096,4096] 32 MB
    unsigned short* ub    = (unsigned short*)(ws + MB(32));  // bf16 [4096,2048] 16 MB
    unsigned short* delta = (unsigned short*)(ws + MB(48));  // bf16 [4096,2048] 16 MB
    float*          xdbl  = (float*)(ws + MB(64));           // fp32 [4096,96]  1.5 MB
    unsigned short* ygb   = (unsigned short*)(ws + MB(66));  // bf16 [4096,2048] 16 MB
    float*          S     = (float*)(ws + MB(82));           // 16 MB (also x_proj partials)
    float*          dsum  = (float*)(ws + MB(98));           // 1 MB
    float*          hin   = (float*)(ws + MB(99));           // 16 MB
    unsigned short* xb    = (unsigned short*)(ws + MB(115)); // bf16 x      8 MB
    unsigned short* wb1   = (unsigned short*)(ws + MB(123)); // bf16 in_w   8 MB
    unsigned short* wb3   = (unsigned short*)(ws + MB(131)); // bf16 xproj  0.4 MB
    unsigned short* wb6   = (unsigned short*)(ws + MB(132)); // bf16 out_w  4 MB
    unsigned short* wb5   = (unsigned short*)(ws + MB(136)); // bf16 dtproj_w 0.25 MB
    unsigned short* dtb   = (unsigned short*)(ws + MB(137)); // bf16 dt [4096,64] 0.5 MB
    float*          xdbl_part = S;                           // 8 x [4096,96] = 12.6 MB

    dim3 blk(256);

    // 0) all fp32->bf16 casts in one launch
    cast_all<<<dim3((C4_TOT + 255) / 256), blk, 0, stream>>>(x, xb, in_w, wb1, xproj_w, wb3,
                                                             out_w, wb6, dtproj_w, wb5);

    // 1) in_proj: xzb = bf16(x @ in_w^T)   [4096 x 4096], K=1024
    gemm_db<1><<<dim3(32, 32), blk, 0, stream>>>(xb, wb1, xzb, nullptr,
                                                 BLTOK, 2 * DI, DM, DM, DM, 2 * DI);

    // 2) conv + silu -> ub (bf16)
    conv_silu_kernel<<<dim3(BLTOK), blk, 0, stream>>>(xzb, conv_w, conv_b, ub);

    // 3) x_proj split-K=8: partials then reduce (fp32 xdbl + bf16 dt copy)
    gemm_mfma_sk<<<dim3(1, 32, 8), blk, 0, stream>>>(ub, wb3, xdbl_part,
                                                     BLTOK, DTR + 2 * NST, DI, DI, DI, 96, 8);
    sk_reduce<<<dim3((BLTOK * 96 / 4 + 255) / 256), blk, 0, stream>>>(xdbl_part, xdbl, dtb,
                                                                      BLTOK * 96 / 4, 8);

    // 4) dt_proj + softplus -> bf16 delta  [4096 x 2048], K=64 (MFMA)
    gemm_db<3><<<dim3(16, 32), blk, 0, stream>>>(dtb, wb5, delta, dtproj_b,
                                                 BLTOK, DI, DTR, DTR, DTR, DI);

    // 5) chunked selective scan (CH=64, LC=32; P replaced by dsum)
    scan_phase1<<<dim3(DI / 256, CH, NB), blk, 0, stream>>>(delta, ub, xdbl, A_log, S, dsum);
    scan_phase2<<<dim3(NB * DI * NST / 256), blk, 0, stream>>>(S, dsum, A_log, hin);
    scan_phase3<<<dim3(DI / 256, CH, NB), blk, 0, stream>>>(delta, ub, xdbl, A_log, Dskip,
                                                            xzb, hin, ygb);

    // 6) out_proj: out = yg @ out_w^T   [4096 x 1024], K=2048
    gemm_db<0><<<dim3(8, 32), blk, 0, stream>>>(ygb, wb6, out, nullptr,
                                                BLTOK, DM, DI, DI, DI, DM);
}